// Round 14
// baseline (315.332 us; speedup 1.0000x reference)
//
#include <hip/hip_runtime.h>
#include <hip/hip_fp16.h>

#define NN 100000
#define NE 1200000
#define NBUK ((NN + 127) / 128)   // 782
#define NCHUNK 128                // blocks in pass A

typedef _Float16 h8 __attribute__((ext_vector_type(8)));
typedef float f32x4 __attribute__((ext_vector_type(4)));

// ---------------- bucketed CSR build ----------------
__global__ __launch_bounds__(1024) void k_zerob(int* bcnt, int* degcnt) {
    int i = threadIdx.x;
    if (i <= NBUK) bcnt[i] = 0;
    if (i < 64) degcnt[i] = 0;
}

__global__ __launch_bounds__(256) void k_bhist(const int* __restrict__ col, int* __restrict__ bcnt) {
    __shared__ int lh[NBUK];
    for (int i = threadIdx.x; i < NBUK; i += 256) lh[i] = 0;
    __syncthreads();
    for (int e = blockIdx.x * 256 + threadIdx.x; e < NE; e += 256 * 256)
        atomicAdd(&lh[col[e] >> 7], 1);
    __syncthreads();
    for (int i = threadIdx.x; i < NBUK; i += 256) {
        int v = lh[i];
        if (v) atomicAdd(&bcnt[i], v);
    }
}

__global__ __launch_bounds__(1024) void k_bscan(int* __restrict__ bcnt, int* __restrict__ bcur) {
    __shared__ int s[1024];
    int tid = threadIdx.x;
    int v = (tid < NBUK) ? bcnt[tid] : 0;
    s[tid] = v;
    __syncthreads();
    #pragma unroll
    for (int d = 1; d < 1024; d <<= 1) {
        int t = (tid >= d) ? s[tid - d] : 0;
        __syncthreads();
        s[tid] += t;
        __syncthreads();
    }
    if (tid < NBUK) {
        int excl = s[tid] - v;
        bcnt[tid] = excl;
        bcur[tid] = excl;
    }
    if (tid == 0) bcnt[NBUK] = NE;
}

__global__ __launch_bounds__(256) void k_bucket(const int* __restrict__ row,
                                                const int* __restrict__ col,
                                                int* __restrict__ bcur,
                                                unsigned* __restrict__ tmp) {
    __shared__ int lh[NBUK];
    const int tid = threadIdx.x;
    const int per = (NE + NCHUNK - 1) / NCHUNK;
    const int e0 = blockIdx.x * per;
    const int e1 = (e0 + per < NE) ? (e0 + per) : NE;
    for (int i = tid; i < NBUK; i += 256) lh[i] = 0;
    __syncthreads();
    for (int e = e0 + tid; e < e1; e += 256)
        atomicAdd(&lh[col[e] >> 7], 1);
    __syncthreads();
    for (int b = tid; b < NBUK; b += 256) {
        int c = lh[b];
        if (c) lh[b] = atomicAdd(&bcur[b], c);
    }
    __syncthreads();
    for (int e = e0 + tid; e < e1; e += 256) {
        int c = col[e], r = row[e];
        int pos = atomicAdd(&lh[c >> 7], 1);
        tmp[pos] = ((unsigned)r << 7) | (unsigned)(c & 127);
    }
}

__global__ __launch_bounds__(256) void k_build(const unsigned* __restrict__ tmp,
                                               const int* __restrict__ bbase,
                                               int* __restrict__ off,
                                               float* __restrict__ dinv,
                                               int* __restrict__ csr_row) {
    __shared__ int cnt[128], s[128], cur[128];
    const int b = blockIdx.x, tid = threadIdx.x;
    const int colBase = b << 7;
    const int nCols = (NN - colBase < 128) ? (NN - colBase) : 128;
    const int seg0 = bbase[b], seg1 = bbase[b + 1];
    if (tid < 128) cnt[tid] = 0;
    __syncthreads();
    for (int i = seg0 + tid; i < seg1; i += 256)
        atomicAdd(&cnt[tmp[i] & 127], 1);
    __syncthreads();
    if (tid < 128) s[tid] = cnt[tid];
    __syncthreads();
    #pragma unroll
    for (int d = 1; d < 128; d <<= 1) {
        int t = (tid < 128 && tid >= d) ? s[tid - d] : 0;
        __syncthreads();
        if (tid < 128) s[tid] += t;
        __syncthreads();
    }
    if (tid < nCols) {
        int exc = seg0 + s[tid] - cnt[tid];
        off[colBase + tid] = exc;
        cur[tid] = exc;
        dinv[colBase + tid] = rsqrtf((float)cnt[tid] + 1.0f);
    }
    if (b == 0 && tid == 0) off[NN] = NE;
    __syncthreads();
    for (int i = seg0 + tid; i < seg1; i += 256) {
        unsigned v = tmp[i];
        int pos = atomicAdd(&cur[v & 127u], 1);
        csr_row[pos] = (int)(v >> 7);
    }
}

// ---------------- degree-sorted node permutation (counting sort, 64 bins) ----------------
__global__ __launch_bounds__(256) void k_deghist(const int* __restrict__ off, int* __restrict__ degcnt) {
    __shared__ int dh[64];
    int tid = threadIdx.x;
    if (tid < 64) dh[tid] = 0;
    __syncthreads();
    int i = blockIdx.x * 256 + tid;
    if (i < NN) {
        int d = off[i + 1] - off[i]; if (d > 63) d = 63;
        atomicAdd(&dh[d], 1);
    }
    __syncthreads();
    if (tid < 64) {
        int v = dh[tid];
        if (v) atomicAdd(&degcnt[tid], v);
    }
}

__global__ __launch_bounds__(64) void k_degscan(int* __restrict__ degcnt, int* __restrict__ degcur) {
    __shared__ int s[64];
    int tid = threadIdx.x;
    int v = degcnt[tid];
    s[tid] = v;
    __syncthreads();
    #pragma unroll
    for (int d = 1; d < 64; d <<= 1) {
        int t = (tid >= d) ? s[tid - d] : 0;
        __syncthreads();
        s[tid] += t;
        __syncthreads();
    }
    degcur[tid] = s[tid] - v;
}

__global__ __launch_bounds__(256) void k_perm(const int* __restrict__ off,
                                              int* __restrict__ degcur,
                                              int* __restrict__ perm) {
    __shared__ int dh[64];
    int tid = threadIdx.x;
    if (tid < 64) dh[tid] = 0;
    __syncthreads();
    int i = blockIdx.x * 256 + tid;
    int d = -1;
    if (i < NN) {
        d = off[i + 1] - off[i]; if (d > 63) d = 63;
        atomicAdd(&dh[d], 1);
    }
    __syncthreads();
    if (tid < 64) {
        int c = dh[tid];
        if (c) dh[tid] = atomicAdd(&degcur[tid], c);
    }
    __syncthreads();
    if (i < NN) {
        int pos = atomicAdd(&dh[d], 1);
        perm[pos] = i;
    }
}

// ---------------- proj GEMM (D=128): LDS-staged W, byp folded as 5th MFMA n-tile ----------------
__global__ __launch_bounds__(256) void k_gemmP(const float* __restrict__ X,
                                               const float* __restrict__ W,
                                               const float* __restrict__ bias,
                                               _Float16* __restrict__ Yh,
                                               const float* __restrict__ bypW,
                                               const float* __restrict__ bypb,
                                               float* __restrict__ bypOut,
                                               int n_nodes) {
    constexpr int D = 128, RS = D + 8, KS = D / 32;
    __shared__ _Float16 Xh[64 * RS];     // 17.4 KB
    __shared__ _Float16 Wh[64 * RS];     // 17.4 KB
    const int tid = threadIdx.x;
    const int n0 = blockIdx.x * 64;

    for (int i = tid; i < 64 * (D / 8); i += 256) {
        int j = i / (D / 8), d8 = (i % (D / 8)) * 8;
        const float4* wp = (const float4*)&W[j * D + d8];
        float4 w0 = wp[0], w1 = wp[1];
        h8 h = { (_Float16)w0.x, (_Float16)w0.y, (_Float16)w0.z, (_Float16)w0.w,
                 (_Float16)w1.x, (_Float16)w1.y, (_Float16)w1.z, (_Float16)w1.w };
        *(h8*)&Wh[j * RS + d8] = h;
    }
    for (int i = tid; i < 64 * (D / 8); i += 256) {
        int nl = i / (D / 8), d8 = (i % (D / 8)) * 8;
        int n = n0 + nl; if (n >= n_nodes) n = n_nodes - 1;
        const float4* xp = (const float4*)&X[(size_t)n * D + d8];
        float4 x0 = xp[0], x1 = xp[1];
        h8 h = { (_Float16)x0.x, (_Float16)x0.y, (_Float16)x0.z, (_Float16)x0.w,
                 (_Float16)x1.x, (_Float16)x1.y, (_Float16)x1.z, (_Float16)x1.w };
        *(h8*)&Xh[nl * RS + d8] = h;
    }
    __syncthreads();

    const int wid = tid >> 6, lane = tid & 63;
    const int lm = lane & 15, lq = lane >> 4;
    const int mBase = wid * 16;

    h8 bfrag[4][KS];
    #pragma unroll
    for (int t = 0; t < 4; ++t)
        #pragma unroll
        for (int s = 0; s < KS; ++s)
            bfrag[t][s] = *(const h8*)&Wh[(t * 16 + lm) * RS + s * 32 + lq * 8];

    h8 bfragB[KS];
    #pragma unroll
    for (int s = 0; s < KS; ++s) {
        if (lm < 3) {
            const float4* wp = (const float4*)&bypW[lm * D + s * 32 + lq * 8];
            float4 w0 = wp[0], w1 = wp[1];
            bfragB[s] = (h8){ (_Float16)w0.x, (_Float16)w0.y, (_Float16)w0.z, (_Float16)w0.w,
                              (_Float16)w1.x, (_Float16)w1.y, (_Float16)w1.z, (_Float16)w1.w };
        } else {
            bfragB[s] = (h8)(_Float16)0;
        }
    }

    f32x4 acc[5] = {};
    #pragma unroll
    for (int s = 0; s < KS; ++s) {
        h8 a = *(const h8*)&Xh[(mBase + lm) * RS + s * 32 + lq * 8];
        #pragma unroll
        for (int t = 0; t < 4; ++t)
            acc[t] = __builtin_amdgcn_mfma_f32_16x16x32_f16(a, bfrag[t][s], acc[t], 0, 0, 0);
        acc[4] = __builtin_amdgcn_mfma_f32_16x16x32_f16(a, bfragB[s], acc[4], 0, 0, 0);
    }

    float bb[4];
    #pragma unroll
    for (int t = 0; t < 4; ++t) bb[t] = bias[t * 16 + lm];
    float bypbv = (lm < 3) ? bypb[lm] : 0.f;
    const int nodeBase = n0 + mBase + lq * 4;
    #pragma unroll
    for (int r = 0; r < 4; ++r) {
        int node = nodeBase + r;
        if (node < n_nodes) {
            #pragma unroll
            for (int t = 0; t < 4; ++t)
                Yh[(size_t)node * 64 + t * 16 + lm] = (_Float16)(acc[t][r] + bb[t]);
            if (lm < 3)
                bypOut[node * 3 + lm] = acc[4][r] + bypbv;
        }
    }
}

// ---------------- conv GEMM (D=64): fp16 A straight copy, Wh LDS, out fp16 * dinv ----------------
__global__ __launch_bounds__(256) void k_gemmC(const _Float16* __restrict__ Xhg,
                                               const float* __restrict__ W,
                                               const float* __restrict__ dinv,
                                               _Float16* __restrict__ Yh,
                                               int n_nodes) {
    constexpr int D = 64, RS = D + 8, KS = D / 32;
    __shared__ _Float16 Xh[64 * RS];     // 9.2 KB
    __shared__ _Float16 Wh[64 * RS];     // 9.2 KB
    const int tid = threadIdx.x;
    const int n0 = blockIdx.x * 64;

    for (int i = tid; i < 64 * (D / 8); i += 256) {
        int j = i / (D / 8), d8 = (i % (D / 8)) * 8;
        const float4* wp = (const float4*)&W[j * D + d8];
        float4 w0 = wp[0], w1 = wp[1];
        h8 h = { (_Float16)w0.x, (_Float16)w0.y, (_Float16)w0.z, (_Float16)w0.w,
                 (_Float16)w1.x, (_Float16)w1.y, (_Float16)w1.z, (_Float16)w1.w };
        *(h8*)&Wh[j * RS + d8] = h;
    }
    for (int i = tid; i < 64 * (D / 8); i += 256) {
        int nl = i / (D / 8), d8 = (i % (D / 8)) * 8;
        int n = n0 + nl; if (n >= n_nodes) n = n_nodes - 1;
        *(h8*)&Xh[nl * RS + d8] = *(const h8*)&Xhg[(size_t)n * D + d8];
    }
    __syncthreads();

    const int wid = tid >> 6, lane = tid & 63;
    const int lm = lane & 15, lq = lane >> 4;
    const int mBase = wid * 16;

    h8 bfrag[4][KS];
    #pragma unroll
    for (int t = 0; t < 4; ++t)
        #pragma unroll
        for (int s = 0; s < KS; ++s)
            bfrag[t][s] = *(const h8*)&Wh[(t * 16 + lm) * RS + s * 32 + lq * 8];

    f32x4 acc[4] = {};
    #pragma unroll
    for (int s = 0; s < KS; ++s) {
        h8 a = *(const h8*)&Xh[(mBase + lm) * RS + s * 32 + lq * 8];
        #pragma unroll
        for (int t = 0; t < 4; ++t)
            acc[t] = __builtin_amdgcn_mfma_f32_16x16x32_f16(a, bfrag[t][s], acc[t], 0, 0, 0);
    }

    const int nodeBase = n0 + mBase + lq * 4;
    #pragma unroll
    for (int r = 0; r < 4; ++r) {
        int node = nodeBase + r;
        if (node < n_nodes) {
            float sdv = dinv[node];
            #pragma unroll
            for (int t = 0; t < 4; ++t)
                Yh[(size_t)node * 64 + t * 16 + lm] = (_Float16)(acc[t][r] * sdv);
        }
    }
}

// ---------------- pull-aggregation: 8 nodes/wave (degree-sorted), 8 lanes/node ----------------
template<bool RES, bool HEAD>
__global__ __launch_bounds__(256) void k_gather(const _Float16* __restrict__ hBh,
                                                const float* __restrict__ dinv,
                                                const int* __restrict__ off,
                                                const int* __restrict__ csr_row,
                                                const int* __restrict__ perm,
                                                const float* __restrict__ convb,
                                                const float* __restrict__ bng,
                                                const float* __restrict__ bnb,
                                                _Float16* __restrict__ hA,
                                                const float* __restrict__ byp,
                                                const float* __restrict__ headW,
                                                const float* __restrict__ headb,
                                                float* __restrict__ out) {
    __shared__ float HWs[HEAD ? 204 : 1];
    const int tid = threadIdx.x;
    if constexpr (HEAD) {
        for (int i = tid; i < 204; i += 256)
            HWs[i] = (i < 201) ? headW[i] : headb[i - 201];
        __syncthreads();
    }
    const int wid = tid >> 6, lane = tid & 63;
    const int slot = blockIdx.x * 32 + wid * 8 + (lane >> 3);   // grid = NN/32 exactly
    const int n = perm[slot];                                   // degree-sorted
    const int oct = lane & 7;
    const int f0 = oct * 8;

    const int e0 = off[n], eEnd = off[n + 1];
    const int deg = eEnd - e0;
    int m = deg;
    #pragma unroll
    for (int mask = 8; mask < 64; mask <<= 1) {
        int o = __shfl_xor(m, mask, 64);
        m = (o > m) ? o : m;
    }

    h8 acch = *(const h8*)(hBh + ((size_t)n << 6) + f0);   // self-loop term
    const h8 zero = (h8)(_Float16)0;
    for (int it = 0; it < m; it += 2) {
        bool v0 = it < deg, v1 = it + 1 < deg;
        int i0 = e0 + it, i1 = i0 + 1;
        int r0 = csr_row[v0 ? i0 : 0];
        int r1 = csr_row[v1 ? i1 : 0];
        h8 raw0 = *(const h8*)(hBh + ((size_t)r0 << 6) + f0);
        h8 raw1 = *(const h8*)(hBh + ((size_t)r1 << 6) + f0);
        acch = acch + (v0 ? raw0 : zero);
        acch = acch + (v1 ? raw1 : zero);
    }

    const float dv = dinv[n];
    const float bnscale = rsqrtf(1.0f + 1e-5f);
    const float4 cb0 = *(const float4*)&convb[f0], cb1 = *(const float4*)&convb[f0 + 4];
    const float4 g0  = *(const float4*)&bng[f0],  g1  = *(const float4*)&bng[f0 + 4];
    const float4 b0_ = *(const float4*)&bnb[f0],  b1_ = *(const float4*)&bnb[f0 + 4];
    const float cb[8] = { cb0.x, cb0.y, cb0.z, cb0.w, cb1.x, cb1.y, cb1.z, cb1.w };
    const float gg[8] = { g0.x, g0.y, g0.z, g0.w, g1.x, g1.y, g1.z, g1.w };
    const float bb[8] = { b0_.x, b0_.y, b0_.z, b0_.w, b1_.x, b1_.y, b1_.z, b1_.w };
    float v[8];
    #pragma unroll
    for (int j = 0; j < 8; ++j)
        v[j] = fmaxf(((float)acch[j] * dv + cb[j]) * (gg[j] * bnscale) + bb[j], 0.0f);

    if constexpr (!HEAD) {
        size_t o = ((size_t)n << 6) + f0;
        if constexpr (RES) {
            h8 old = *(const h8*)&hA[o];
            #pragma unroll
            for (int j = 0; j < 8; ++j) v[j] += (float)old[j];
        }
        h8 res = { (_Float16)v[0], (_Float16)v[1], (_Float16)v[2], (_Float16)v[3],
                   (_Float16)v[4], (_Float16)v[5], (_Float16)v[6], (_Float16)v[7] };
        *(h8*)&hA[o] = res;
    } else {
        float p[3];
        #pragma unroll
        for (int o = 0; o < 3; ++o) {
            float t = 0.f;
            #pragma unroll
            for (int j = 0; j < 8; ++j) t += v[j] * HWs[o * 67 + f0 + j];
            p[o] = t;
        }
        #pragma unroll
        for (int mask = 1; mask < 8; mask <<= 1) {
            #pragma unroll
            for (int o = 0; o < 3; ++o) p[o] += __shfl_xor(p[o], mask, 64);
        }
        if (oct == 0) {
            float by0 = byp[n * 3], by1 = byp[n * 3 + 1], by2 = byp[n * 3 + 2];
            #pragma unroll
            for (int o = 0; o < 3; ++o)
                p[o] += by0 * HWs[o * 67 + 64] + by1 * HWs[o * 67 + 65] + by2 * HWs[o * 67 + 66]
                      + HWs[201 + o];
            float kappa = fminf(fmaxf(p[0] * 5.0f + 2.5f, 0.2f), 10.0f);
            float tau   = fminf(fmaxf(p[2] + 0.5f, 0.05f), 2.0f);
            out[(size_t)n * 3]     = kappa;
            out[(size_t)n * 3 + 1] = p[1];
            out[(size_t)n * 3 + 2] = tau;
        }
    }
}

extern "C" void kernel_launch(void* const* d_in, const int* in_sizes, int n_in,
                              void* d_out, int out_size, void* d_ws, size_t ws_size,
                              hipStream_t stream) {
    const float* x     = (const float*)d_in[0];
    const int*   ei    = (const int*)d_in[1];
    const int*   row   = ei;
    const int*   col   = ei + NE;
    const float* projW = (const float*)d_in[2];
    const float* projb = (const float*)d_in[3];
    const float* convW[3] = { (const float*)d_in[4], (const float*)d_in[8],  (const float*)d_in[12] };
    const float* convb[3] = { (const float*)d_in[5], (const float*)d_in[9],  (const float*)d_in[13] };
    const float* bng[3]   = { (const float*)d_in[6], (const float*)d_in[10], (const float*)d_in[14] };
    const float* bnb[3]   = { (const float*)d_in[7], (const float*)d_in[11], (const float*)d_in[15] };
    const float* bypW  = (const float*)d_in[16];
    const float* bypb  = (const float*)d_in[17];
    const float* headW = (const float*)d_in[18];
    const float* headb = (const float*)d_in[19];
    float* out = (float*)d_out;

    float*    ws   = (float*)d_ws;
    float*    dinv = ws;                                   // 102400 floats
    _Float16* hAh  = (_Float16*)(ws + 102400);             // NN*64 fp16
    _Float16* hBh  = hAh + (size_t)NN * 64;                // NN*64 fp16
    float*    byp  = (float*)(hBh + (size_t)NN * 64);      // NN*3 (+pad)
    int*      off     = (int*)(byp + 300032);              // NN+1 (pad 100096)
    int*      csr_row = off + 100096;                      // NE
    int*      bcnt    = csr_row + NE;                      // NBUK+1 (pad 784)
    int*      bcur    = bcnt + 784;                        // NBUK (pad 784)
    int*      perm    = bcur + 784;                        // NN (pad 100096)
    int*      degcnt  = perm + 100096;                     // 64
    int*      degcur  = degcnt + 64;                       // 64
    unsigned* tmp     = (unsigned*)hAh;                    // aliases hAh (consumed before proj)

    // bucketed CSR build (+dinv +off)
    k_zerob<<<1, 1024, 0, stream>>>(bcnt, degcnt);
    k_bhist<<<256, 256, 0, stream>>>(col, bcnt);
    k_bscan<<<1, 1024, 0, stream>>>(bcnt, bcur);
    k_bucket<<<NCHUNK, 256, 0, stream>>>(row, col, bcur, tmp);
    k_build<<<NBUK, 256, 0, stream>>>(tmp, bcnt, off, dinv, csr_row);

    // degree-sorted node permutation
    k_deghist<<<(NN + 255) / 256, 256, 0, stream>>>(off, degcnt);
    k_degscan<<<1, 64, 0, stream>>>(degcnt, degcur);
    k_perm<<<(NN + 255) / 256, 256, 0, stream>>>(off, degcur, perm);

    // proj: hAh = fp16(x @ projW.T + projb), byp = x @ bypW.T + bypb (fused MFMA tile)
    k_gemmP<<<(NN + 63) / 64, 256, 0, stream>>>(x, projW, projb, hAh, bypW, bypb, byp, NN);

    for (int l = 0; l < 3; l++) {
        // hBh = fp16((hAh @ convW.T) * dinv)
        k_gemmC<<<(NN + 63) / 64, 256, 0, stream>>>(hAh, convW[l], dinv, hBh, NN);
        if (l < 2)
            k_gather<true, false><<<NN / 32, 256, 0, stream>>>(
                hBh, dinv, off, csr_row, perm, convb[l], bng[l], bnb[l], hAh,
                nullptr, nullptr, nullptr, nullptr);
        else
            k_gather<false, true><<<NN / 32, 256, 0, stream>>>(
                hBh, dinv, off, csr_row, perm, convb[l], bng[l], bnb[l], nullptr,
                byp, headW, headb, out);
    }
}

// Round 15
// 314.840 us; speedup vs baseline: 1.0016x; 1.0016x over previous
//
#include <hip/hip_runtime.h>
#include <hip/hip_fp16.h>

#define NN 100000
#define NE 1200000
#define NBUK ((NN + 127) / 128)   // 782
#define NCHUNK 128                // blocks in pass A
#define WSZ 1024                  // degree-sort window (nodes)
#define NWIN ((NN + WSZ - 1) / WSZ)   // 98

typedef _Float16 h8 __attribute__((ext_vector_type(8)));
typedef float f32x4 __attribute__((ext_vector_type(4)));

// ---------------- bucketed CSR build ----------------
__global__ __launch_bounds__(1024) void k_zerob(int* bcnt) {
    int i = threadIdx.x;
    if (i <= NBUK) bcnt[i] = 0;
}

__global__ __launch_bounds__(256) void k_bhist(const int* __restrict__ col, int* __restrict__ bcnt) {
    __shared__ int lh[NBUK];
    for (int i = threadIdx.x; i < NBUK; i += 256) lh[i] = 0;
    __syncthreads();
    for (int e = blockIdx.x * 256 + threadIdx.x; e < NE; e += 256 * 256)
        atomicAdd(&lh[col[e] >> 7], 1);
    __syncthreads();
    for (int i = threadIdx.x; i < NBUK; i += 256) {
        int v = lh[i];
        if (v) atomicAdd(&bcnt[i], v);
    }
}

__global__ __launch_bounds__(1024) void k_bscan(int* __restrict__ bcnt, int* __restrict__ bcur) {
    __shared__ int s[1024];
    int tid = threadIdx.x;
    int v = (tid < NBUK) ? bcnt[tid] : 0;
    s[tid] = v;
    __syncthreads();
    #pragma unroll
    for (int d = 1; d < 1024; d <<= 1) {
        int t = (tid >= d) ? s[tid - d] : 0;
        __syncthreads();
        s[tid] += t;
        __syncthreads();
    }
    if (tid < NBUK) {
        int excl = s[tid] - v;
        bcnt[tid] = excl;
        bcur[tid] = excl;
    }
    if (tid == 0) bcnt[NBUK] = NE;
}

__global__ __launch_bounds__(256) void k_bucket(const int* __restrict__ row,
                                                const int* __restrict__ col,
                                                int* __restrict__ bcur,
                                                unsigned* __restrict__ tmp) {
    __shared__ int lh[NBUK];
    const int tid = threadIdx.x;
    const int per = (NE + NCHUNK - 1) / NCHUNK;
    const int e0 = blockIdx.x * per;
    const int e1 = (e0 + per < NE) ? (e0 + per) : NE;
    for (int i = tid; i < NBUK; i += 256) lh[i] = 0;
    __syncthreads();
    for (int e = e0 + tid; e < e1; e += 256)
        atomicAdd(&lh[col[e] >> 7], 1);
    __syncthreads();
    for (int b = tid; b < NBUK; b += 256) {
        int c = lh[b];
        if (c) lh[b] = atomicAdd(&bcur[b], c);
    }
    __syncthreads();
    for (int e = e0 + tid; e < e1; e += 256) {
        int c = col[e], r = row[e];
        int pos = atomicAdd(&lh[c >> 7], 1);
        tmp[pos] = ((unsigned)r << 7) | (unsigned)(c & 127);
    }
}

__global__ __launch_bounds__(256) void k_build(const unsigned* __restrict__ tmp,
                                               const int* __restrict__ bbase,
                                               int* __restrict__ off,
                                               float* __restrict__ dinv,
                                               int* __restrict__ csr_row) {
    __shared__ int cnt[128], s[128], cur[128];
    const int b = blockIdx.x, tid = threadIdx.x;
    const int colBase = b << 7;
    const int nCols = (NN - colBase < 128) ? (NN - colBase) : 128;
    const int seg0 = bbase[b], seg1 = bbase[b + 1];
    if (tid < 128) cnt[tid] = 0;
    __syncthreads();
    for (int i = seg0 + tid; i < seg1; i += 256)
        atomicAdd(&cnt[tmp[i] & 127], 1);
    __syncthreads();
    if (tid < 128) s[tid] = cnt[tid];
    __syncthreads();
    #pragma unroll
    for (int d = 1; d < 128; d <<= 1) {
        int t = (tid < 128 && tid >= d) ? s[tid - d] : 0;
        __syncthreads();
        if (tid < 128) s[tid] += t;
        __syncthreads();
    }
    if (tid < nCols) {
        int exc = seg0 + s[tid] - cnt[tid];
        off[colBase + tid] = exc;
        cur[tid] = exc;
        dinv[colBase + tid] = rsqrtf((float)cnt[tid] + 1.0f);
    }
    if (b == 0 && tid == 0) off[NN] = NE;
    __syncthreads();
    for (int i = seg0 + tid; i < seg1; i += 256) {
        unsigned v = tmp[i];
        int pos = atomicAdd(&cur[v & 127u], 1);
        csr_row[pos] = (int)(v >> 7);
    }
}

// ---------------- windowed degree sort: counting sort within 1024-node windows ----------------
__global__ __launch_bounds__(256) void k_wsort(const int* __restrict__ off, int* __restrict__ perm) {
    __shared__ int cnt[64], cur[64];
    const int tid = threadIdx.x;
    const int wbase = blockIdx.x * WSZ;
    const int nNodes = (NN - wbase < WSZ) ? (NN - wbase) : WSZ;
    if (tid < 64) cnt[tid] = 0;
    __syncthreads();
    for (int i = tid; i < nNodes; i += 256) {
        int n = wbase + i;
        int d = off[n + 1] - off[n]; if (d > 63) d = 63;
        atomicAdd(&cnt[d], 1);
    }
    __syncthreads();
    if (tid < 64) cur[tid] = cnt[tid];
    __syncthreads();
    #pragma unroll
    for (int d = 1; d < 64; d <<= 1) {
        int t = (tid < 64 && tid >= d) ? cur[tid - d] : 0;
        __syncthreads();
        if (tid < 64) cur[tid] += t;
        __syncthreads();
    }
    if (tid < 64) cur[tid] -= cnt[tid];   // exclusive
    __syncthreads();
    for (int i = tid; i < nNodes; i += 256) {
        int n = wbase + i;
        int d = off[n + 1] - off[n]; if (d > 63) d = 63;
        int pos = atomicAdd(&cur[d], 1);
        perm[wbase + pos] = n;
    }
}

// ---------------- proj GEMM (D=128): LDS-staged W, byp folded as 5th MFMA n-tile ----------------
__global__ __launch_bounds__(256) void k_gemmP(const float* __restrict__ X,
                                               const float* __restrict__ W,
                                               const float* __restrict__ bias,
                                               _Float16* __restrict__ Yh,
                                               const float* __restrict__ bypW,
                                               const float* __restrict__ bypb,
                                               float* __restrict__ bypOut,
                                               int n_nodes) {
    constexpr int D = 128, RS = D + 8, KS = D / 32;
    __shared__ _Float16 Xh[64 * RS];
    __shared__ _Float16 Wh[64 * RS];
    const int tid = threadIdx.x;
    const int n0 = blockIdx.x * 64;

    for (int i = tid; i < 64 * (D / 8); i += 256) {
        int j = i / (D / 8), d8 = (i % (D / 8)) * 8;
        const float4* wp = (const float4*)&W[j * D + d8];
        float4 w0 = wp[0], w1 = wp[1];
        h8 h = { (_Float16)w0.x, (_Float16)w0.y, (_Float16)w0.z, (_Float16)w0.w,
                 (_Float16)w1.x, (_Float16)w1.y, (_Float16)w1.z, (_Float16)w1.w };
        *(h8*)&Wh[j * RS + d8] = h;
    }
    for (int i = tid; i < 64 * (D / 8); i += 256) {
        int nl = i / (D / 8), d8 = (i % (D / 8)) * 8;
        int n = n0 + nl; if (n >= n_nodes) n = n_nodes - 1;
        const float4* xp = (const float4*)&X[(size_t)n * D + d8];
        float4 x0 = xp[0], x1 = xp[1];
        h8 h = { (_Float16)x0.x, (_Float16)x0.y, (_Float16)x0.z, (_Float16)x0.w,
                 (_Float16)x1.x, (_Float16)x1.y, (_Float16)x1.z, (_Float16)x1.w };
        *(h8*)&Xh[nl * RS + d8] = h;
    }
    __syncthreads();

    const int wid = tid >> 6, lane = tid & 63;
    const int lm = lane & 15, lq = lane >> 4;
    const int mBase = wid * 16;

    h8 bfrag[4][KS];
    #pragma unroll
    for (int t = 0; t < 4; ++t)
        #pragma unroll
        for (int s = 0; s < KS; ++s)
            bfrag[t][s] = *(const h8*)&Wh[(t * 16 + lm) * RS + s * 32 + lq * 8];

    h8 bfragB[KS];
    #pragma unroll
    for (int s = 0; s < KS; ++s) {
        if (lm < 3) {
            const float4* wp = (const float4*)&bypW[lm * D + s * 32 + lq * 8];
            float4 w0 = wp[0], w1 = wp[1];
            bfragB[s] = (h8){ (_Float16)w0.x, (_Float16)w0.y, (_Float16)w0.z, (_Float16)w0.w,
                              (_Float16)w1.x, (_Float16)w1.y, (_Float16)w1.z, (_Float16)w1.w };
        } else {
            bfragB[s] = (h8)(_Float16)0;
        }
    }

    f32x4 acc[5] = {};
    #pragma unroll
    for (int s = 0; s < KS; ++s) {
        h8 a = *(const h8*)&Xh[(mBase + lm) * RS + s * 32 + lq * 8];
        #pragma unroll
        for (int t = 0; t < 4; ++t)
            acc[t] = __builtin_amdgcn_mfma_f32_16x16x32_f16(a, bfrag[t][s], acc[t], 0, 0, 0);
        acc[4] = __builtin_amdgcn_mfma_f32_16x16x32_f16(a, bfragB[s], acc[4], 0, 0, 0);
    }

    float bb[4];
    #pragma unroll
    for (int t = 0; t < 4; ++t) bb[t] = bias[t * 16 + lm];
    float bypbv = (lm < 3) ? bypb[lm] : 0.f;
    const int nodeBase = n0 + mBase + lq * 4;
    #pragma unroll
    for (int r = 0; r < 4; ++r) {
        int node = nodeBase + r;
        if (node < n_nodes) {
            #pragma unroll
            for (int t = 0; t < 4; ++t)
                Yh[(size_t)node * 64 + t * 16 + lm] = (_Float16)(acc[t][r] + bb[t]);
            if (lm < 3)
                bypOut[node * 3 + lm] = acc[4][r] + bypbv;
        }
    }
}

// ---------------- conv GEMM (D=64): fp16 A straight copy, Wh LDS, out fp16 * dinv ----------------
__global__ __launch_bounds__(256) void k_gemmC(const _Float16* __restrict__ Xhg,
                                               const float* __restrict__ W,
                                               const float* __restrict__ dinv,
                                               _Float16* __restrict__ Yh,
                                               int n_nodes) {
    constexpr int D = 64, RS = D + 8, KS = D / 32;
    __shared__ _Float16 Xh[64 * RS];
    __shared__ _Float16 Wh[64 * RS];
    const int tid = threadIdx.x;
    const int n0 = blockIdx.x * 64;

    for (int i = tid; i < 64 * (D / 8); i += 256) {
        int j = i / (D / 8), d8 = (i % (D / 8)) * 8;
        const float4* wp = (const float4*)&W[j * D + d8];
        float4 w0 = wp[0], w1 = wp[1];
        h8 h = { (_Float16)w0.x, (_Float16)w0.y, (_Float16)w0.z, (_Float16)w0.w,
                 (_Float16)w1.x, (_Float16)w1.y, (_Float16)w1.z, (_Float16)w1.w };
        *(h8*)&Wh[j * RS + d8] = h;
    }
    for (int i = tid; i < 64 * (D / 8); i += 256) {
        int nl = i / (D / 8), d8 = (i % (D / 8)) * 8;
        int n = n0 + nl; if (n >= n_nodes) n = n_nodes - 1;
        *(h8*)&Xh[nl * RS + d8] = *(const h8*)&Xhg[(size_t)n * D + d8];
    }
    __syncthreads();

    const int wid = tid >> 6, lane = tid & 63;
    const int lm = lane & 15, lq = lane >> 4;
    const int mBase = wid * 16;

    h8 bfrag[4][KS];
    #pragma unroll
    for (int t = 0; t < 4; ++t)
        #pragma unroll
        for (int s = 0; s < KS; ++s)
            bfrag[t][s] = *(const h8*)&Wh[(t * 16 + lm) * RS + s * 32 + lq * 8];

    f32x4 acc[4] = {};
    #pragma unroll
    for (int s = 0; s < KS; ++s) {
        h8 a = *(const h8*)&Xh[(mBase + lm) * RS + s * 32 + lq * 8];
        #pragma unroll
        for (int t = 0; t < 4; ++t)
            acc[t] = __builtin_amdgcn_mfma_f32_16x16x32_f16(a, bfrag[t][s], acc[t], 0, 0, 0);
    }

    const int nodeBase = n0 + mBase + lq * 4;
    #pragma unroll
    for (int r = 0; r < 4; ++r) {
        int node = nodeBase + r;
        if (node < n_nodes) {
            float sdv = dinv[node];
            #pragma unroll
            for (int t = 0; t < 4; ++t)
                Yh[(size_t)node * 64 + t * 16 + lm] = (_Float16)(acc[t][r] * sdv);
        }
    }
}

// ---------------- pull-aggregation: 8 nodes/wave (window-degree-sorted), 8 lanes/node ----------------
template<bool RES, bool HEAD>
__global__ __launch_bounds__(256) void k_gather(const _Float16* __restrict__ hBh,
                                                const float* __restrict__ dinv,
                                                const int* __restrict__ off,
                                                const int* __restrict__ csr_row,
                                                const int* __restrict__ perm,
                                                const float* __restrict__ convb,
                                                const float* __restrict__ bng,
                                                const float* __restrict__ bnb,
                                                _Float16* __restrict__ hA,
                                                const float* __restrict__ byp,
                                                const float* __restrict__ headW,
                                                const float* __restrict__ headb,
                                                float* __restrict__ out) {
    __shared__ float HWs[HEAD ? 204 : 1];
    const int tid = threadIdx.x;
    if constexpr (HEAD) {
        for (int i = tid; i < 204; i += 256)
            HWs[i] = (i < 201) ? headW[i] : headb[i - 201];
        __syncthreads();
    }
    const int wid = tid >> 6, lane = tid & 63;
    const int slot = blockIdx.x * 32 + wid * 8 + (lane >> 3);   // grid = NN/32 exactly
    const int n = perm[slot];                                   // window-degree-sorted
    const int oct = lane & 7;
    const int f0 = oct * 8;

    const int e0 = off[n], eEnd = off[n + 1];
    const int deg = eEnd - e0;
    int m = deg;
    #pragma unroll
    for (int mask = 8; mask < 64; mask <<= 1) {
        int o = __shfl_xor(m, mask, 64);
        m = (o > m) ? o : m;
    }

    h8 acch = *(const h8*)(hBh + ((size_t)n << 6) + f0);   // self-loop term
    const h8 zero = (h8)(_Float16)0;
    for (int it = 0; it < m; it += 2) {
        bool v0 = it < deg, v1 = it + 1 < deg;
        int i0 = e0 + it, i1 = i0 + 1;
        int r0 = csr_row[v0 ? i0 : 0];
        int r1 = csr_row[v1 ? i1 : 0];
        h8 raw0 = *(const h8*)(hBh + ((size_t)r0 << 6) + f0);
        h8 raw1 = *(const h8*)(hBh + ((size_t)r1 << 6) + f0);
        acch = acch + (v0 ? raw0 : zero);
        acch = acch + (v1 ? raw1 : zero);
    }

    const float dv = dinv[n];
    const float bnscale = rsqrtf(1.0f + 1e-5f);
    const float4 cb0 = *(const float4*)&convb[f0], cb1 = *(const float4*)&convb[f0 + 4];
    const float4 g0  = *(const float4*)&bng[f0],  g1  = *(const float4*)&bng[f0 + 4];
    const float4 b0_ = *(const float4*)&bnb[f0],  b1_ = *(const float4*)&bnb[f0 + 4];
    const float cb[8] = { cb0.x, cb0.y, cb0.z, cb0.w, cb1.x, cb1.y, cb1.z, cb1.w };
    const float gg[8] = { g0.x, g0.y, g0.z, g0.w, g1.x, g1.y, g1.z, g1.w };
    const float bb[8] = { b0_.x, b0_.y, b0_.z, b0_.w, b1_.x, b1_.y, b1_.z, b1_.w };
    float v[8];
    #pragma unroll
    for (int j = 0; j < 8; ++j)
        v[j] = fmaxf(((float)acch[j] * dv + cb[j]) * (gg[j] * bnscale) + bb[j], 0.0f);

    if constexpr (!HEAD) {
        size_t o = ((size_t)n << 6) + f0;
        if constexpr (RES) {
            h8 old = *(const h8*)&hA[o];
            #pragma unroll
            for (int j = 0; j < 8; ++j) v[j] += (float)old[j];
        }
        h8 res = { (_Float16)v[0], (_Float16)v[1], (_Float16)v[2], (_Float16)v[3],
                   (_Float16)v[4], (_Float16)v[5], (_Float16)v[6], (_Float16)v[7] };
        *(h8*)&hA[o] = res;
    } else {
        float p[3];
        #pragma unroll
        for (int o = 0; o < 3; ++o) {
            float t = 0.f;
            #pragma unroll
            for (int j = 0; j < 8; ++j) t += v[j] * HWs[o * 67 + f0 + j];
            p[o] = t;
        }
        #pragma unroll
        for (int mask = 1; mask < 8; mask <<= 1) {
            #pragma unroll
            for (int o = 0; o < 3; ++o) p[o] += __shfl_xor(p[o], mask, 64);
        }
        if (oct == 0) {
            float by0 = byp[n * 3], by1 = byp[n * 3 + 1], by2 = byp[n * 3 + 2];
            #pragma unroll
            for (int o = 0; o < 3; ++o)
                p[o] += by0 * HWs[o * 67 + 64] + by1 * HWs[o * 67 + 65] + by2 * HWs[o * 67 + 66]
                      + HWs[201 + o];
            float kappa = fminf(fmaxf(p[0] * 5.0f + 2.5f, 0.2f), 10.0f);
            float tau   = fminf(fmaxf(p[2] + 0.5f, 0.05f), 2.0f);
            out[(size_t)n * 3]     = kappa;
            out[(size_t)n * 3 + 1] = p[1];
            out[(size_t)n * 3 + 2] = tau;
        }
    }
}

extern "C" void kernel_launch(void* const* d_in, const int* in_sizes, int n_in,
                              void* d_out, int out_size, void* d_ws, size_t ws_size,
                              hipStream_t stream) {
    const float* x     = (const float*)d_in[0];
    const int*   ei    = (const int*)d_in[1];
    const int*   row   = ei;
    const int*   col   = ei + NE;
    const float* projW = (const float*)d_in[2];
    const float* projb = (const float*)d_in[3];
    const float* convW[3] = { (const float*)d_in[4], (const float*)d_in[8],  (const float*)d_in[12] };
    const float* convb[3] = { (const float*)d_in[5], (const float*)d_in[9],  (const float*)d_in[13] };
    const float* bng[3]   = { (const float*)d_in[6], (const float*)d_in[10], (const float*)d_in[14] };
    const float* bnb[3]   = { (const float*)d_in[7], (const float*)d_in[11], (const float*)d_in[15] };
    const float* bypW  = (const float*)d_in[16];
    const float* bypb  = (const float*)d_in[17];
    const float* headW = (const float*)d_in[18];
    const float* headb = (const float*)d_in[19];
    float* out = (float*)d_out;

    float*    ws   = (float*)d_ws;
    float*    dinv = ws;                                   // 102400 floats
    _Float16* hAh  = (_Float16*)(ws + 102400);             // NN*64 fp16
    _Float16* hBh  = hAh + (size_t)NN * 64;                // NN*64 fp16
    float*    byp  = (float*)(hBh + (size_t)NN * 64);      // NN*3 (+pad)
    int*      off     = (int*)(byp + 300032);              // NN+1 (pad 100096)
    int*      csr_row = off + 100096;                      // NE
    int*      bcnt    = csr_row + NE;                      // NBUK+1 (pad 784)
    int*      bcur    = bcnt + 784;                        // NBUK (pad 784)
    int*      perm    = bcur + 784;                        // NN (pad 100096)
    unsigned* tmp     = (unsigned*)hAh;                    // aliases hAh (consumed before proj)

    // bucketed CSR build (+dinv +off)
    k_zerob<<<1, 1024, 0, stream>>>(bcnt);
    k_bhist<<<256, 256, 0, stream>>>(col, bcnt);
    k_bscan<<<1, 1024, 0, stream>>>(bcnt, bcur);
    k_bucket<<<NCHUNK, 256, 0, stream>>>(row, col, bcur, tmp);
    k_build<<<NBUK, 256, 0, stream>>>(tmp, bcnt, off, dinv, csr_row);

    // windowed degree sort (locality-preserving)
    k_wsort<<<NWIN, 256, 0, stream>>>(off, perm);

    // proj: hAh = fp16(x @ projW.T + projb), byp = x @ bypW.T + bypb (fused MFMA tile)
    k_gemmP<<<(NN + 63) / 64, 256, 0, stream>>>(x, projW, projb, hAh, bypW, bypb, byp, NN);

    for (int l = 0; l < 3; l++) {
        // hBh = fp16((hAh @ convW.T) * dinv)
        k_gemmC<<<(NN + 63) / 64, 256, 0, stream>>>(hAh, convW[l], dinv, hBh, NN);
        if (l < 2)
            k_gather<true, false><<<NN / 32, 256, 0, stream>>>(
                hBh, dinv, off, csr_row, perm, convb[l], bng[l], bnb[l], hAh,
                nullptr, nullptr, nullptr, nullptr);
        else
            k_gather<false, true><<<NN / 32, 256, 0, stream>>>(
                hBh, dinv, off, csr_row, perm, convb[l], bng[l], bnb[l], nullptr,
                byp, headW, headb, out);
    }
}

// Round 16
// 285.873 us; speedup vs baseline: 1.1031x; 1.1013x over previous
//
#include <hip/hip_runtime.h>
#include <hip/hip_fp16.h>

#define NN 100000
#define NE 1200000
#define NBUK ((NN + 127) / 128)   // 782
#define NCHUNK 128                // blocks in pass A

typedef _Float16 h8 __attribute__((ext_vector_type(8)));
typedef float f32x4 __attribute__((ext_vector_type(4)));

// ---------------- bucketed CSR build ----------------
__global__ __launch_bounds__(1024) void k_zerob(int* bcnt) {
    int i = threadIdx.x;
    if (i <= NBUK) bcnt[i] = 0;
}

__global__ __launch_bounds__(256) void k_bhist(const int* __restrict__ col, int* __restrict__ bcnt) {
    __shared__ int lh[NBUK];
    for (int i = threadIdx.x; i < NBUK; i += 256) lh[i] = 0;
    __syncthreads();
    for (int e = blockIdx.x * 256 + threadIdx.x; e < NE; e += 256 * 256)
        atomicAdd(&lh[col[e] >> 7], 1);
    __syncthreads();
    for (int i = threadIdx.x; i < NBUK; i += 256) {
        int v = lh[i];
        if (v) atomicAdd(&bcnt[i], v);
    }
}

__global__ __launch_bounds__(1024) void k_bscan(int* __restrict__ bcnt, int* __restrict__ bcur) {
    __shared__ int s[1024];
    int tid = threadIdx.x;
    int v = (tid < NBUK) ? bcnt[tid] : 0;
    s[tid] = v;
    __syncthreads();
    #pragma unroll
    for (int d = 1; d < 1024; d <<= 1) {
        int t = (tid >= d) ? s[tid - d] : 0;
        __syncthreads();
        s[tid] += t;
        __syncthreads();
    }
    if (tid < NBUK) {
        int excl = s[tid] - v;
        bcnt[tid] = excl;
        bcur[tid] = excl;
    }
    if (tid == 0) bcnt[NBUK] = NE;
}

__global__ __launch_bounds__(256) void k_bucket(const int* __restrict__ row,
                                                const int* __restrict__ col,
                                                int* __restrict__ bcur,
                                                unsigned* __restrict__ tmp) {
    __shared__ int lh[NBUK];
    const int tid = threadIdx.x;
    const int per = (NE + NCHUNK - 1) / NCHUNK;
    const int e0 = blockIdx.x * per;
    const int e1 = (e0 + per < NE) ? (e0 + per) : NE;
    for (int i = tid; i < NBUK; i += 256) lh[i] = 0;
    __syncthreads();
    for (int e = e0 + tid; e < e1; e += 256)
        atomicAdd(&lh[col[e] >> 7], 1);
    __syncthreads();
    for (int b = tid; b < NBUK; b += 256) {
        int c = lh[b];
        if (c) lh[b] = atomicAdd(&bcur[b], c);
    }
    __syncthreads();
    for (int e = e0 + tid; e < e1; e += 256) {
        int c = col[e], r = row[e];
        int pos = atomicAdd(&lh[c >> 7], 1);
        tmp[pos] = ((unsigned)r << 7) | (unsigned)(c & 127);
    }
}

__global__ __launch_bounds__(256) void k_build(const unsigned* __restrict__ tmp,
                                               const int* __restrict__ bbase,
                                               int* __restrict__ off,
                                               float* __restrict__ dinv,
                                               int* __restrict__ csr_row) {
    __shared__ int cnt[128], s[128], cur[128];
    const int b = blockIdx.x, tid = threadIdx.x;
    const int colBase = b << 7;
    const int nCols = (NN - colBase < 128) ? (NN - colBase) : 128;
    const int seg0 = bbase[b], seg1 = bbase[b + 1];
    if (tid < 128) cnt[tid] = 0;
    __syncthreads();
    for (int i = seg0 + tid; i < seg1; i += 256)
        atomicAdd(&cnt[tmp[i] & 127], 1);
    __syncthreads();
    if (tid < 128) s[tid] = cnt[tid];
    __syncthreads();
    #pragma unroll
    for (int d = 1; d < 128; d <<= 1) {
        int t = (tid < 128 && tid >= d) ? s[tid - d] : 0;
        __syncthreads();
        if (tid < 128) s[tid] += t;
        __syncthreads();
    }
    if (tid < nCols) {
        int exc = seg0 + s[tid] - cnt[tid];
        off[colBase + tid] = exc;
        cur[tid] = exc;
        dinv[colBase + tid] = rsqrtf((float)cnt[tid] + 1.0f);
    }
    if (b == 0 && tid == 0) off[NN] = NE;
    __syncthreads();
    for (int i = seg0 + tid; i < seg1; i += 256) {
        unsigned v = tmp[i];
        int pos = atomicAdd(&cur[v & 127u], 1);
        csr_row[pos] = (int)(v >> 7);
    }
}

// ---------------- proj GEMM (D=128): LDS-staged W, byp folded as 5th MFMA n-tile ----------------
__global__ __launch_bounds__(256) void k_gemmP(const float* __restrict__ X,
                                               const float* __restrict__ W,
                                               const float* __restrict__ bias,
                                               _Float16* __restrict__ Yh,
                                               const float* __restrict__ bypW,
                                               const float* __restrict__ bypb,
                                               float* __restrict__ bypOut,
                                               int n_nodes) {
    constexpr int D = 128, RS = D + 8, KS = D / 32;
    __shared__ _Float16 Xh[64 * RS];
    __shared__ _Float16 Wh[64 * RS];
    const int tid = threadIdx.x;
    const int n0 = blockIdx.x * 64;

    for (int i = tid; i < 64 * (D / 8); i += 256) {
        int j = i / (D / 8), d8 = (i % (D / 8)) * 8;
        const float4* wp = (const float4*)&W[j * D + d8];
        float4 w0 = wp[0], w1 = wp[1];
        h8 h = { (_Float16)w0.x, (_Float16)w0.y, (_Float16)w0.z, (_Float16)w0.w,
                 (_Float16)w1.x, (_Float16)w1.y, (_Float16)w1.z, (_Float16)w1.w };
        *(h8*)&Wh[j * RS + d8] = h;
    }
    for (int i = tid; i < 64 * (D / 8); i += 256) {
        int nl = i / (D / 8), d8 = (i % (D / 8)) * 8;
        int n = n0 + nl; if (n >= n_nodes) n = n_nodes - 1;
        const float4* xp = (const float4*)&X[(size_t)n * D + d8];
        float4 x0 = xp[0], x1 = xp[1];
        h8 h = { (_Float16)x0.x, (_Float16)x0.y, (_Float16)x0.z, (_Float16)x0.w,
                 (_Float16)x1.x, (_Float16)x1.y, (_Float16)x1.z, (_Float16)x1.w };
        *(h8*)&Xh[nl * RS + d8] = h;
    }
    __syncthreads();

    const int wid = tid >> 6, lane = tid & 63;
    const int lm = lane & 15, lq = lane >> 4;
    const int mBase = wid * 16;

    h8 bfrag[4][KS];
    #pragma unroll
    for (int t = 0; t < 4; ++t)
        #pragma unroll
        for (int s = 0; s < KS; ++s)
            bfrag[t][s] = *(const h8*)&Wh[(t * 16 + lm) * RS + s * 32 + lq * 8];

    h8 bfragB[KS];
    #pragma unroll
    for (int s = 0; s < KS; ++s) {
        if (lm < 3) {
            const float4* wp = (const float4*)&bypW[lm * D + s * 32 + lq * 8];
            float4 w0 = wp[0], w1 = wp[1];
            bfragB[s] = (h8){ (_Float16)w0.x, (_Float16)w0.y, (_Float16)w0.z, (_Float16)w0.w,
                              (_Float16)w1.x, (_Float16)w1.y, (_Float16)w1.z, (_Float16)w1.w };
        } else {
            bfragB[s] = (h8)(_Float16)0;
        }
    }

    f32x4 acc[5] = {};
    #pragma unroll
    for (int s = 0; s < KS; ++s) {
        h8 a = *(const h8*)&Xh[(mBase + lm) * RS + s * 32 + lq * 8];
        #pragma unroll
        for (int t = 0; t < 4; ++t)
            acc[t] = __builtin_amdgcn_mfma_f32_16x16x32_f16(a, bfrag[t][s], acc[t], 0, 0, 0);
        acc[4] = __builtin_amdgcn_mfma_f32_16x16x32_f16(a, bfragB[s], acc[4], 0, 0, 0);
    }

    float bb[4];
    #pragma unroll
    for (int t = 0; t < 4; ++t) bb[t] = bias[t * 16 + lm];
    float bypbv = (lm < 3) ? bypb[lm] : 0.f;
    const int nodeBase = n0 + mBase + lq * 4;
    #pragma unroll
    for (int r = 0; r < 4; ++r) {
        int node = nodeBase + r;
        if (node < n_nodes) {
            #pragma unroll
            for (int t = 0; t < 4; ++t)
                Yh[(size_t)node * 64 + t * 16 + lm] = (_Float16)(acc[t][r] + bb[t]);
            if (lm < 3)
                bypOut[node * 3 + lm] = acc[4][r] + bypbv;
        }
    }
}

// ---------------- conv GEMM (D=64): fp16 A straight copy, Wh LDS, out fp16 * dinv ----------------
__global__ __launch_bounds__(256) void k_gemmC(const _Float16* __restrict__ Xhg,
                                               const float* __restrict__ W,
                                               const float* __restrict__ dinv,
                                               _Float16* __restrict__ Yh,
                                               int n_nodes) {
    constexpr int D = 64, RS = D + 8, KS = D / 32;
    __shared__ _Float16 Xh[64 * RS];
    __shared__ _Float16 Wh[64 * RS];
    const int tid = threadIdx.x;
    const int n0 = blockIdx.x * 64;

    for (int i = tid; i < 64 * (D / 8); i += 256) {
        int j = i / (D / 8), d8 = (i % (D / 8)) * 8;
        const float4* wp = (const float4*)&W[j * D + d8];
        float4 w0 = wp[0], w1 = wp[1];
        h8 h = { (_Float16)w0.x, (_Float16)w0.y, (_Float16)w0.z, (_Float16)w0.w,
                 (_Float16)w1.x, (_Float16)w1.y, (_Float16)w1.z, (_Float16)w1.w };
        *(h8*)&Wh[j * RS + d8] = h;
    }
    for (int i = tid; i < 64 * (D / 8); i += 256) {
        int nl = i / (D / 8), d8 = (i % (D / 8)) * 8;
        int n = n0 + nl; if (n >= n_nodes) n = n_nodes - 1;
        *(h8*)&Xh[nl * RS + d8] = *(const h8*)&Xhg[(size_t)n * D + d8];
    }
    __syncthreads();

    const int wid = tid >> 6, lane = tid & 63;
    const int lm = lane & 15, lq = lane >> 4;
    const int mBase = wid * 16;

    h8 bfrag[4][KS];
    #pragma unroll
    for (int t = 0; t < 4; ++t)
        #pragma unroll
        for (int s = 0; s < KS; ++s)
            bfrag[t][s] = *(const h8*)&Wh[(t * 16 + lm) * RS + s * 32 + lq * 8];

    f32x4 acc[4] = {};
    #pragma unroll
    for (int s = 0; s < KS; ++s) {
        h8 a = *(const h8*)&Xh[(mBase + lm) * RS + s * 32 + lq * 8];
        #pragma unroll
        for (int t = 0; t < 4; ++t)
            acc[t] = __builtin_amdgcn_mfma_f32_16x16x32_f16(a, bfrag[t][s], acc[t], 0, 0, 0);
    }

    const int nodeBase = n0 + mBase + lq * 4;
    #pragma unroll
    for (int r = 0; r < 4; ++r) {
        int node = nodeBase + r;
        if (node < n_nodes) {
            float sdv = dinv[node];
            #pragma unroll
            for (int t = 0; t < 4; ++t)
                Yh[(size_t)node * 64 + t * 16 + lm] = (_Float16)(acc[t][r] * sdv);
        }
    }
}

// ---------------- pull-aggregation: 8 nodes/wave, 8 lanes/node, 4 loads in flight ----------------
template<bool RES, bool HEAD>
__global__ __launch_bounds__(256) void k_gather(const _Float16* __restrict__ hBh,
                                                const float* __restrict__ dinv,
                                                const int* __restrict__ off,
                                                const int* __restrict__ csr_row,
                                                const float* __restrict__ convb,
                                                const float* __restrict__ bng,
                                                const float* __restrict__ bnb,
                                                _Float16* __restrict__ hA,
                                                const float* __restrict__ byp,
                                                const float* __restrict__ headW,
                                                const float* __restrict__ headb,
                                                float* __restrict__ out) {
    __shared__ float HWs[HEAD ? 204 : 1];
    const int tid = threadIdx.x;
    if constexpr (HEAD) {
        for (int i = tid; i < 204; i += 256)
            HWs[i] = (i < 201) ? headW[i] : headb[i - 201];
        __syncthreads();
    }
    const int wid = tid >> 6, lane = tid & 63;
    const int n = blockIdx.x * 32 + wid * 8 + (lane >> 3);   // grid = NN/32 exactly
    const int oct = lane & 7;
    const int f0 = oct * 8;

    const int e0 = off[n], eEnd = off[n + 1];
    const int deg = eEnd - e0;
    int m = deg;
    #pragma unroll
    for (int mask = 8; mask < 64; mask <<= 1) {
        int o = __shfl_xor(m, mask, 64);
        m = (o > m) ? o : m;
    }

    h8 acch = *(const h8*)(hBh + ((size_t)n << 6) + f0);   // self-loop term
    const h8 zero = (h8)(_Float16)0;
    for (int it = 0; it < m; it += 4) {
        bool v0 = it < deg, v1 = it + 1 < deg, v2 = it + 2 < deg, v3 = it + 3 < deg;
        int i0 = e0 + it;
        int r0 = csr_row[v0 ? i0 : 0];
        int r1 = csr_row[v1 ? i0 + 1 : 0];
        int r2 = csr_row[v2 ? i0 + 2 : 0];
        int r3 = csr_row[v3 ? i0 + 3 : 0];
        h8 raw0 = *(const h8*)(hBh + ((size_t)r0 << 6) + f0);
        h8 raw1 = *(const h8*)(hBh + ((size_t)r1 << 6) + f0);
        h8 raw2 = *(const h8*)(hBh + ((size_t)r2 << 6) + f0);
        h8 raw3 = *(const h8*)(hBh + ((size_t)r3 << 6) + f0);
        acch = acch + (v0 ? raw0 : zero);
        acch = acch + (v1 ? raw1 : zero);
        acch = acch + (v2 ? raw2 : zero);
        acch = acch + (v3 ? raw3 : zero);
    }

    const float dv = dinv[n];
    const float bnscale = rsqrtf(1.0f + 1e-5f);
    const float4 cb0 = *(const float4*)&convb[f0], cb1 = *(const float4*)&convb[f0 + 4];
    const float4 g0  = *(const float4*)&bng[f0],  g1  = *(const float4*)&bng[f0 + 4];
    const float4 b0_ = *(const float4*)&bnb[f0],  b1_ = *(const float4*)&bnb[f0 + 4];
    const float cb[8] = { cb0.x, cb0.y, cb0.z, cb0.w, cb1.x, cb1.y, cb1.z, cb1.w };
    const float gg[8] = { g0.x, g0.y, g0.z, g0.w, g1.x, g1.y, g1.z, g1.w };
    const float bb[8] = { b0_.x, b0_.y, b0_.z, b0_.w, b1_.x, b1_.y, b1_.z, b1_.w };
    float v[8];
    #pragma unroll
    for (int j = 0; j < 8; ++j)
        v[j] = fmaxf(((float)acch[j] * dv + cb[j]) * (gg[j] * bnscale) + bb[j], 0.0f);

    if constexpr (!HEAD) {
        size_t o = ((size_t)n << 6) + f0;
        if constexpr (RES) {
            h8 old = *(const h8*)&hA[o];
            #pragma unroll
            for (int j = 0; j < 8; ++j) v[j] += (float)old[j];
        }
        h8 res = { (_Float16)v[0], (_Float16)v[1], (_Float16)v[2], (_Float16)v[3],
                   (_Float16)v[4], (_Float16)v[5], (_Float16)v[6], (_Float16)v[7] };
        *(h8*)&hA[o] = res;
    } else {
        float p[3];
        #pragma unroll
        for (int o = 0; o < 3; ++o) {
            float t = 0.f;
            #pragma unroll
            for (int j = 0; j < 8; ++j) t += v[j] * HWs[o * 67 + f0 + j];
            p[o] = t;
        }
        #pragma unroll
        for (int mask = 1; mask < 8; mask <<= 1) {
            #pragma unroll
            for (int o = 0; o < 3; ++o) p[o] += __shfl_xor(p[o], mask, 64);
        }
        if (oct == 0) {
            float by0 = byp[n * 3], by1 = byp[n * 3 + 1], by2 = byp[n * 3 + 2];
            #pragma unroll
            for (int o = 0; o < 3; ++o)
                p[o] += by0 * HWs[o * 67 + 64] + by1 * HWs[o * 67 + 65] + by2 * HWs[o * 67 + 66]
                      + HWs[201 + o];
            float kappa = fminf(fmaxf(p[0] * 5.0f + 2.5f, 0.2f), 10.0f);
            float tau   = fminf(fmaxf(p[2] + 0.5f, 0.05f), 2.0f);
            out[(size_t)n * 3]     = kappa;
            out[(size_t)n * 3 + 1] = p[1];
            out[(size_t)n * 3 + 2] = tau;
        }
    }
}

extern "C" void kernel_launch(void* const* d_in, const int* in_sizes, int n_in,
                              void* d_out, int out_size, void* d_ws, size_t ws_size,
                              hipStream_t stream) {
    const float* x     = (const float*)d_in[0];
    const int*   ei    = (const int*)d_in[1];
    const int*   row   = ei;
    const int*   col   = ei + NE;
    const float* projW = (const float*)d_in[2];
    const float* projb = (const float*)d_in[3];
    const float* convW[3] = { (const float*)d_in[4], (const float*)d_in[8],  (const float*)d_in[12] };
    const float* convb[3] = { (const float*)d_in[5], (const float*)d_in[9],  (const float*)d_in[13] };
    const float* bng[3]   = { (const float*)d_in[6], (const float*)d_in[10], (const float*)d_in[14] };
    const float* bnb[3]   = { (const float*)d_in[7], (const float*)d_in[11], (const float*)d_in[15] };
    const float* bypW  = (const float*)d_in[16];
    const float* bypb  = (const float*)d_in[17];
    const float* headW = (const float*)d_in[18];
    const float* headb = (const float*)d_in[19];
    float* out = (float*)d_out;

    float*    ws   = (float*)d_ws;
    float*    dinv = ws;                                   // 102400 floats
    _Float16* hAh  = (_Float16*)(ws + 102400);             // NN*64 fp16
    _Float16* hBh  = hAh + (size_t)NN * 64;                // NN*64 fp16
    float*    byp  = (float*)(hBh + (size_t)NN * 64);      // NN*3 (+pad)
    int*      off     = (int*)(byp + 300032);              // NN+1 (pad 100096)
    int*      csr_row = off + 100096;                      // NE
    int*      bcnt    = csr_row + NE;                      // NBUK+1 (pad 784)
    int*      bcur    = bcnt + 784;                        // NBUK
    unsigned* tmp     = (unsigned*)hAh;                    // aliases hAh (consumed before proj)

    // bucketed CSR build (+dinv +off)
    k_zerob<<<1, 1024, 0, stream>>>(bcnt);
    k_bhist<<<256, 256, 0, stream>>>(col, bcnt);
    k_bscan<<<1, 1024, 0, stream>>>(bcnt, bcur);
    k_bucket<<<NCHUNK, 256, 0, stream>>>(row, col, bcur, tmp);
    k_build<<<NBUK, 256, 0, stream>>>(tmp, bcnt, off, dinv, csr_row);

    // proj: hAh = fp16(x @ projW.T + projb), byp = x @ bypW.T + bypb (fused MFMA tile)
    k_gemmP<<<(NN + 63) / 64, 256, 0, stream>>>(x, projW, projb, hAh, bypW, bypb, byp, NN);

    for (int l = 0; l < 3; l++) {
        // hBh = fp16((hAh @ convW.T) * dinv)
        k_gemmC<<<(NN + 63) / 64, 256, 0, stream>>>(hAh, convW[l], dinv, hBh, NN);
        if (l < 2)
            k_gather<true, false><<<NN / 32, 256, 0, stream>>>(
                hBh, dinv, off, csr_row, convb[l], bng[l], bnb[l], hAh,
                nullptr, nullptr, nullptr, nullptr);
        else
            k_gather<false, true><<<NN / 32, 256, 0, stream>>>(
                hBh, dinv, off, csr_row, convb[l], bng[l], bnb[l], nullptr,
                byp, headW, headb, out);
    }
}

// Round 17
// 281.502 us; speedup vs baseline: 1.1202x; 1.0155x over previous
//
#include <hip/hip_runtime.h>
#include <hip/hip_fp16.h>

#define NN 100000
#define NE 1200000
#define NBUK ((NN + 127) / 128)   // 782
#define NCHUNK 128                // chunks in bucket passes

typedef _Float16 h8 __attribute__((ext_vector_type(8)));
typedef float f32x4 __attribute__((ext_vector_type(4)));

// ---------------- deterministic two-phase bucketed CSR build ----------------
// pass A: per-chunk LDS histogram -> blkcnt[bucket*NCHUNK + chunk] (plain writes)
__global__ __launch_bounds__(256) void k_bucketA(const int* __restrict__ col,
                                                 int* __restrict__ blkcnt) {
    __shared__ int lh[NBUK];
    const int tid = threadIdx.x;
    const int per = (NE + NCHUNK - 1) / NCHUNK;
    const int e0 = blockIdx.x * per;
    const int e1 = (e0 + per < NE) ? (e0 + per) : NE;
    for (int i = tid; i < NBUK; i += 256) lh[i] = 0;
    __syncthreads();
    for (int e = e0 + tid; e < e1; e += 256)
        atomicAdd(&lh[col[e] >> 7], 1);
    __syncthreads();
    for (int b = tid; b < NBUK; b += 256)
        blkcnt[b * NCHUNK + blockIdx.x] = lh[b];
}

// per-bucket exclusive scan over its NCHUNK chunk-counts; total -> bcnt[b]
__global__ __launch_bounds__(128) void k_colscan(int* __restrict__ blkcnt, int* __restrict__ bcnt) {
    __shared__ int s[NCHUNK];
    const int b = blockIdx.x, tid = threadIdx.x;
    int v = blkcnt[b * NCHUNK + tid];
    s[tid] = v;
    __syncthreads();
    #pragma unroll
    for (int d = 1; d < NCHUNK; d <<= 1) {
        int t = (tid >= d) ? s[tid - d] : 0;
        __syncthreads();
        s[tid] += t;
        __syncthreads();
    }
    blkcnt[b * NCHUNK + tid] = s[tid] - v;   // exclusive prefix within bucket
    if (tid == NCHUNK - 1) bcnt[b] = s[NCHUNK - 1];
}

// single-block exclusive scan of bcnt[NBUK] -> bucket bases (in place)
__global__ __launch_bounds__(1024) void k_bscan(int* __restrict__ bcnt) {
    __shared__ int s[1024];
    int tid = threadIdx.x;
    int v = (tid < NBUK) ? bcnt[tid] : 0;
    s[tid] = v;
    __syncthreads();
    #pragma unroll
    for (int d = 1; d < 1024; d <<= 1) {
        int t = (tid >= d) ? s[tid - d] : 0;
        __syncthreads();
        s[tid] += t;
        __syncthreads();
    }
    if (tid < NBUK) bcnt[tid] = s[tid] - v;
    if (tid == 0) bcnt[NBUK] = NE;
}

// pass B: deterministic cursors (base + chunk prefix), LDS-cursor scatter
__global__ __launch_bounds__(256) void k_bucketB(const int* __restrict__ row,
                                                 const int* __restrict__ col,
                                                 const int* __restrict__ bbase,
                                                 const int* __restrict__ blkcnt,
                                                 unsigned* __restrict__ tmp) {
    __shared__ int lh[NBUK];
    const int tid = threadIdx.x;
    const int per = (NE + NCHUNK - 1) / NCHUNK;
    const int e0 = blockIdx.x * per;
    const int e1 = (e0 + per < NE) ? (e0 + per) : NE;
    for (int b = tid; b < NBUK; b += 256)
        lh[b] = bbase[b] + blkcnt[b * NCHUNK + blockIdx.x];
    __syncthreads();
    for (int e = e0 + tid; e < e1; e += 256) {
        int c = col[e], r = row[e];
        int pos = atomicAdd(&lh[c >> 7], 1);
        tmp[pos] = ((unsigned)r << 7) | (unsigned)(c & 127);
    }
}

__global__ __launch_bounds__(256) void k_build(const unsigned* __restrict__ tmp,
                                               const int* __restrict__ bbase,
                                               int* __restrict__ off,
                                               float* __restrict__ dinv,
                                               int* __restrict__ csr_row) {
    __shared__ int cnt[128], s[128], cur[128];
    const int b = blockIdx.x, tid = threadIdx.x;
    const int colBase = b << 7;
    const int nCols = (NN - colBase < 128) ? (NN - colBase) : 128;
    const int seg0 = bbase[b], seg1 = bbase[b + 1];
    if (tid < 128) cnt[tid] = 0;
    __syncthreads();
    for (int i = seg0 + tid; i < seg1; i += 256)
        atomicAdd(&cnt[tmp[i] & 127], 1);
    __syncthreads();
    if (tid < 128) s[tid] = cnt[tid];
    __syncthreads();
    #pragma unroll
    for (int d = 1; d < 128; d <<= 1) {
        int t = (tid < 128 && tid >= d) ? s[tid - d] : 0;
        __syncthreads();
        if (tid < 128) s[tid] += t;
        __syncthreads();
    }
    if (tid < nCols) {
        int exc = seg0 + s[tid] - cnt[tid];
        off[colBase + tid] = exc;
        cur[tid] = exc;
        dinv[colBase + tid] = rsqrtf((float)cnt[tid] + 1.0f);
    }
    if (b == 0 && tid == 0) off[NN] = NE;
    __syncthreads();
    for (int i = seg0 + tid; i < seg1; i += 256) {
        unsigned v = tmp[i];
        int pos = atomicAdd(&cur[v & 127u], 1);
        csr_row[pos] = (int)(v >> 7);
    }
}

// ---------------- proj GEMM (D=128): LDS-staged W, byp folded as 5th MFMA n-tile ----------------
__global__ __launch_bounds__(256) void k_gemmP(const float* __restrict__ X,
                                               const float* __restrict__ W,
                                               const float* __restrict__ bias,
                                               _Float16* __restrict__ Yh,
                                               const float* __restrict__ bypW,
                                               const float* __restrict__ bypb,
                                               float* __restrict__ bypOut,
                                               int n_nodes) {
    constexpr int D = 128, RS = D + 8, KS = D / 32;
    __shared__ _Float16 Xh[64 * RS];
    __shared__ _Float16 Wh[64 * RS];
    const int tid = threadIdx.x;
    const int n0 = blockIdx.x * 64;

    for (int i = tid; i < 64 * (D / 8); i += 256) {
        int j = i / (D / 8), d8 = (i % (D / 8)) * 8;
        const float4* wp = (const float4*)&W[j * D + d8];
        float4 w0 = wp[0], w1 = wp[1];
        h8 h = { (_Float16)w0.x, (_Float16)w0.y, (_Float16)w0.z, (_Float16)w0.w,
                 (_Float16)w1.x, (_Float16)w1.y, (_Float16)w1.z, (_Float16)w1.w };
        *(h8*)&Wh[j * RS + d8] = h;
    }
    for (int i = tid; i < 64 * (D / 8); i += 256) {
        int nl = i / (D / 8), d8 = (i % (D / 8)) * 8;
        int n = n0 + nl; if (n >= n_nodes) n = n_nodes - 1;
        const float4* xp = (const float4*)&X[(size_t)n * D + d8];
        float4 x0 = xp[0], x1 = xp[1];
        h8 h = { (_Float16)x0.x, (_Float16)x0.y, (_Float16)x0.z, (_Float16)x0.w,
                 (_Float16)x1.x, (_Float16)x1.y, (_Float16)x1.z, (_Float16)x1.w };
        *(h8*)&Xh[nl * RS + d8] = h;
    }
    __syncthreads();

    const int wid = tid >> 6, lane = tid & 63;
    const int lm = lane & 15, lq = lane >> 4;
    const int mBase = wid * 16;

    h8 bfrag[4][KS];
    #pragma unroll
    for (int t = 0; t < 4; ++t)
        #pragma unroll
        for (int s = 0; s < KS; ++s)
            bfrag[t][s] = *(const h8*)&Wh[(t * 16 + lm) * RS + s * 32 + lq * 8];

    h8 bfragB[KS];
    #pragma unroll
    for (int s = 0; s < KS; ++s) {
        if (lm < 3) {
            const float4* wp = (const float4*)&bypW[lm * D + s * 32 + lq * 8];
            float4 w0 = wp[0], w1 = wp[1];
            bfragB[s] = (h8){ (_Float16)w0.x, (_Float16)w0.y, (_Float16)w0.z, (_Float16)w0.w,
                              (_Float16)w1.x, (_Float16)w1.y, (_Float16)w1.z, (_Float16)w1.w };
        } else {
            bfragB[s] = (h8)(_Float16)0;
        }
    }

    f32x4 acc[5] = {};
    #pragma unroll
    for (int s = 0; s < KS; ++s) {
        h8 a = *(const h8*)&Xh[(mBase + lm) * RS + s * 32 + lq * 8];
        #pragma unroll
        for (int t = 0; t < 4; ++t)
            acc[t] = __builtin_amdgcn_mfma_f32_16x16x32_f16(a, bfrag[t][s], acc[t], 0, 0, 0);
        acc[4] = __builtin_amdgcn_mfma_f32_16x16x32_f16(a, bfragB[s], acc[4], 0, 0, 0);
    }

    float bb[4];
    #pragma unroll
    for (int t = 0; t < 4; ++t) bb[t] = bias[t * 16 + lm];
    float bypbv = (lm < 3) ? bypb[lm] : 0.f;
    const int nodeBase = n0 + mBase + lq * 4;
    #pragma unroll
    for (int r = 0; r < 4; ++r) {
        int node = nodeBase + r;
        if (node < n_nodes) {
            #pragma unroll
            for (int t = 0; t < 4; ++t)
                Yh[(size_t)node * 64 + t * 16 + lm] = (_Float16)(acc[t][r] + bb[t]);
            if (lm < 3)
                bypOut[node * 3 + lm] = acc[4][r] + bypbv;
        }
    }
}

// ---------------- conv GEMM (D=64): fp16 A straight copy, Wh LDS, out fp16 * dinv ----------------
__global__ __launch_bounds__(256) void k_gemmC(const _Float16* __restrict__ Xhg,
                                               const float* __restrict__ W,
                                               const float* __restrict__ dinv,
                                               _Float16* __restrict__ Yh,
                                               int n_nodes) {
    constexpr int D = 64, RS = D + 8, KS = D / 32;
    __shared__ _Float16 Xh[64 * RS];
    __shared__ _Float16 Wh[64 * RS];
    const int tid = threadIdx.x;
    const int n0 = blockIdx.x * 64;

    for (int i = tid; i < 64 * (D / 8); i += 256) {
        int j = i / (D / 8), d8 = (i % (D / 8)) * 8;
        const float4* wp = (const float4*)&W[j * D + d8];
        float4 w0 = wp[0], w1 = wp[1];
        h8 h = { (_Float16)w0.x, (_Float16)w0.y, (_Float16)w0.z, (_Float16)w0.w,
                 (_Float16)w1.x, (_Float16)w1.y, (_Float16)w1.z, (_Float16)w1.w };
        *(h8*)&Wh[j * RS + d8] = h;
    }
    for (int i = tid; i < 64 * (D / 8); i += 256) {
        int nl = i / (D / 8), d8 = (i % (D / 8)) * 8;
        int n = n0 + nl; if (n >= n_nodes) n = n_nodes - 1;
        *(h8*)&Xh[nl * RS + d8] = *(const h8*)&Xhg[(size_t)n * D + d8];
    }
    __syncthreads();

    const int wid = tid >> 6, lane = tid & 63;
    const int lm = lane & 15, lq = lane >> 4;
    const int mBase = wid * 16;

    h8 bfrag[4][KS];
    #pragma unroll
    for (int t = 0; t < 4; ++t)
        #pragma unroll
        for (int s = 0; s < KS; ++s)
            bfrag[t][s] = *(const h8*)&Wh[(t * 16 + lm) * RS + s * 32 + lq * 8];

    f32x4 acc[4] = {};
    #pragma unroll
    for (int s = 0; s < KS; ++s) {
        h8 a = *(const h8*)&Xh[(mBase + lm) * RS + s * 32 + lq * 8];
        #pragma unroll
        for (int t = 0; t < 4; ++t)
            acc[t] = __builtin_amdgcn_mfma_f32_16x16x32_f16(a, bfrag[t][s], acc[t], 0, 0, 0);
    }

    const int nodeBase = n0 + mBase + lq * 4;
    #pragma unroll
    for (int r = 0; r < 4; ++r) {
        int node = nodeBase + r;
        if (node < n_nodes) {
            float sdv = dinv[node];
            #pragma unroll
            for (int t = 0; t < 4; ++t)
                Yh[(size_t)node * 64 + t * 16 + lm] = (_Float16)(acc[t][r] * sdv);
        }
    }
}

// ---------------- pull-aggregation: 8 nodes/wave, 8 lanes/node, 4 loads in flight ----------------
template<bool RES, bool HEAD>
__global__ __launch_bounds__(256) void k_gather(const _Float16* __restrict__ hBh,
                                                const float* __restrict__ dinv,
                                                const int* __restrict__ off,
                                                const int* __restrict__ csr_row,
                                                const float* __restrict__ convb,
                                                const float* __restrict__ bng,
                                                const float* __restrict__ bnb,
                                                _Float16* __restrict__ hA,
                                                const float* __restrict__ byp,
                                                const float* __restrict__ headW,
                                                const float* __restrict__ headb,
                                                float* __restrict__ out) {
    __shared__ float HWs[HEAD ? 204 : 1];
    const int tid = threadIdx.x;
    if constexpr (HEAD) {
        for (int i = tid; i < 204; i += 256)
            HWs[i] = (i < 201) ? headW[i] : headb[i - 201];
        __syncthreads();
    }
    const int wid = tid >> 6, lane = tid & 63;
    const int n = blockIdx.x * 32 + wid * 8 + (lane >> 3);   // grid = NN/32 exactly
    const int oct = lane & 7;
    const int f0 = oct * 8;

    const int e0 = off[n], eEnd = off[n + 1];
    const int deg = eEnd - e0;
    int m = deg;
    #pragma unroll
    for (int mask = 8; mask < 64; mask <<= 1) {
        int o = __shfl_xor(m, mask, 64);
        m = (o > m) ? o : m;
    }

    h8 acch = *(const h8*)(hBh + ((size_t)n << 6) + f0);   // self-loop term
    const h8 zero = (h8)(_Float16)0;
    for (int it = 0; it < m; it += 4) {
        bool v0 = it < deg, v1 = it + 1 < deg, v2 = it + 2 < deg, v3 = it + 3 < deg;
        int i0 = e0 + it;
        int r0 = csr_row[v0 ? i0 : 0];
        int r1 = csr_row[v1 ? i0 + 1 : 0];
        int r2 = csr_row[v2 ? i0 + 2 : 0];
        int r3 = csr_row[v3 ? i0 + 3 : 0];
        h8 raw0 = *(const h8*)(hBh + ((size_t)r0 << 6) + f0);
        h8 raw1 = *(const h8*)(hBh + ((size_t)r1 << 6) + f0);
        h8 raw2 = *(const h8*)(hBh + ((size_t)r2 << 6) + f0);
        h8 raw3 = *(const h8*)(hBh + ((size_t)r3 << 6) + f0);
        acch = acch + (v0 ? raw0 : zero);
        acch = acch + (v1 ? raw1 : zero);
        acch = acch + (v2 ? raw2 : zero);
        acch = acch + (v3 ? raw3 : zero);
    }

    const float dv = dinv[n];
    const float bnscale = rsqrtf(1.0f + 1e-5f);
    const float4 cb0 = *(const float4*)&convb[f0], cb1 = *(const float4*)&convb[f0 + 4];
    const float4 g0  = *(const float4*)&bng[f0],  g1  = *(const float4*)&bng[f0 + 4];
    const float4 b0_ = *(const float4*)&bnb[f0],  b1_ = *(const float4*)&bnb[f0 + 4];
    const float cb[8] = { cb0.x, cb0.y, cb0.z, cb0.w, cb1.x, cb1.y, cb1.z, cb1.w };
    const float gg[8] = { g0.x, g0.y, g0.z, g0.w, g1.x, g1.y, g1.z, g1.w };
    const float bb[8] = { b0_.x, b0_.y, b0_.z, b0_.w, b1_.x, b1_.y, b1_.z, b1_.w };
    float v[8];
    #pragma unroll
    for (int j = 0; j < 8; ++j)
        v[j] = fmaxf(((float)acch[j] * dv + cb[j]) * (gg[j] * bnscale) + bb[j], 0.0f);

    if constexpr (!HEAD) {
        size_t o = ((size_t)n << 6) + f0;
        if constexpr (RES) {
            h8 old = *(const h8*)&hA[o];
            #pragma unroll
            for (int j = 0; j < 8; ++j) v[j] += (float)old[j];
        }
        h8 res = { (_Float16)v[0], (_Float16)v[1], (_Float16)v[2], (_Float16)v[3],
                   (_Float16)v[4], (_Float16)v[5], (_Float16)v[6], (_Float16)v[7] };
        *(h8*)&hA[o] = res;
    } else {
        float p[3];
        #pragma unroll
        for (int o = 0; o < 3; ++o) {
            float t = 0.f;
            #pragma unroll
            for (int j = 0; j < 8; ++j) t += v[j] * HWs[o * 67 + f0 + j];
            p[o] = t;
        }
        #pragma unroll
        for (int mask = 1; mask < 8; mask <<= 1) {
            #pragma unroll
            for (int o = 0; o < 3; ++o) p[o] += __shfl_xor(p[o], mask, 64);
        }
        if (oct == 0) {
            float by0 = byp[n * 3], by1 = byp[n * 3 + 1], by2 = byp[n * 3 + 2];
            #pragma unroll
            for (int o = 0; o < 3; ++o)
                p[o] += by0 * HWs[o * 67 + 64] + by1 * HWs[o * 67 + 65] + by2 * HWs[o * 67 + 66]
                      + HWs[201 + o];
            float kappa = fminf(fmaxf(p[0] * 5.0f + 2.5f, 0.2f), 10.0f);
            float tau   = fminf(fmaxf(p[2] + 0.5f, 0.05f), 2.0f);
            out[(size_t)n * 3]     = kappa;
            out[(size_t)n * 3 + 1] = p[1];
            out[(size_t)n * 3 + 2] = tau;
        }
    }
}

extern "C" void kernel_launch(void* const* d_in, const int* in_sizes, int n_in,
                              void* d_out, int out_size, void* d_ws, size_t ws_size,
                              hipStream_t stream) {
    const float* x     = (const float*)d_in[0];
    const int*   ei    = (const int*)d_in[1];
    const int*   row   = ei;
    const int*   col   = ei + NE;
    const float* projW = (const float*)d_in[2];
    const float* projb = (const float*)d_in[3];
    const float* convW[3] = { (const float*)d_in[4], (const float*)d_in[8],  (const float*)d_in[12] };
    const float* convb[3] = { (const float*)d_in[5], (const float*)d_in[9],  (const float*)d_in[13] };
    const float* bng[3]   = { (const float*)d_in[6], (const float*)d_in[10], (const float*)d_in[14] };
    const float* bnb[3]   = { (const float*)d_in[7], (const float*)d_in[11], (const float*)d_in[15] };
    const float* bypW  = (const float*)d_in[16];
    const float* bypb  = (const float*)d_in[17];
    const float* headW = (const float*)d_in[18];
    const float* headb = (const float*)d_in[19];
    float* out = (float*)d_out;

    float*    ws   = (float*)d_ws;
    float*    dinv = ws;                                   // 102400 floats
    _Float16* hAh  = (_Float16*)(ws + 102400);             // NN*64 fp16
    _Float16* hBh  = hAh + (size_t)NN * 64;                // NN*64 fp16
    float*    byp  = (float*)(hBh + (size_t)NN * 64);      // NN*3 (+pad)
    int*      off     = (int*)(byp + 300032);              // NN+1 (pad 100096)
    int*      csr_row = off + 100096;                      // NE
    int*      bcnt    = csr_row + NE;                      // NBUK+1 (pad 784)
    int*      blkcnt  = bcnt + 784;                        // NBUK*NCHUNK = 100096
    unsigned* tmp     = (unsigned*)hAh;                    // aliases hAh (consumed before proj)

    // deterministic bucketed CSR build (+dinv +off) — zero global atomics
    k_bucketA<<<NCHUNK, 256, 0, stream>>>(col, blkcnt);
    k_colscan<<<NBUK, 128, 0, stream>>>(blkcnt, bcnt);
    k_bscan<<<1, 1024, 0, stream>>>(bcnt);
    k_bucketB<<<NCHUNK, 256, 0, stream>>>(row, col, bcnt, blkcnt, tmp);
    k_build<<<NBUK, 256, 0, stream>>>(tmp, bcnt, off, dinv, csr_row);

    // proj: hAh = fp16(x @ projW.T + projb), byp = x @ bypW.T + bypb (fused MFMA tile)
    k_gemmP<<<(NN + 63) / 64, 256, 0, stream>>>(x, projW, projb, hAh, bypW, bypb, byp, NN);

    for (int l = 0; l < 3; l++) {
        // hBh = fp16((hAh @ convW.T) * dinv)
        k_gemmC<<<(NN + 63) / 64, 256, 0, stream>>>(hAh, convW[l], dinv, hBh, NN);
        if (l < 2)
            k_gather<true, false><<<NN / 32, 256, 0, stream>>>(
                hBh, dinv, off, csr_row, convb[l], bng[l], bnb[l], hAh,
                nullptr, nullptr, nullptr, nullptr);
        else
            k_gather<false, true><<<NN / 32, 256, 0, stream>>>(
                hBh, dinv, off, csr_row, convb[l], bng[l], bnb[l], nullptr,
                byp, headW, headb, out);
    }
}

// Round 18
// 273.588 us; speedup vs baseline: 1.1526x; 1.0289x over previous
//
#include <hip/hip_runtime.h>
#include <hip/hip_fp16.h>

#define NN 100000
#define NE 1200000
#define NBUK ((NN + 127) / 128)   // 782
#define NCHUNK 128                // chunks in bucket passes

typedef _Float16 h8 __attribute__((ext_vector_type(8)));
typedef float f32x4 __attribute__((ext_vector_type(4)));
typedef float f32x2 __attribute__((ext_vector_type(2)));

// ---------------- deterministic two-phase bucketed CSR build ----------------
__global__ __launch_bounds__(256) void k_bucketA(const int* __restrict__ col,
                                                 int* __restrict__ blkcnt) {
    __shared__ int lh[NBUK];
    const int tid = threadIdx.x;
    const int per = (NE + NCHUNK - 1) / NCHUNK;
    const int e0 = blockIdx.x * per;
    const int e1 = (e0 + per < NE) ? (e0 + per) : NE;
    for (int i = tid; i < NBUK; i += 256) lh[i] = 0;
    __syncthreads();
    for (int e = e0 + tid; e < e1; e += 256)
        atomicAdd(&lh[col[e] >> 7], 1);
    __syncthreads();
    for (int b = tid; b < NBUK; b += 256)
        blkcnt[b * NCHUNK + blockIdx.x] = lh[b];
}

__global__ __launch_bounds__(128) void k_colscan(int* __restrict__ blkcnt, int* __restrict__ bcnt) {
    __shared__ int s[NCHUNK];
    const int b = blockIdx.x, tid = threadIdx.x;
    int v = blkcnt[b * NCHUNK + tid];
    s[tid] = v;
    __syncthreads();
    #pragma unroll
    for (int d = 1; d < NCHUNK; d <<= 1) {
        int t = (tid >= d) ? s[tid - d] : 0;
        __syncthreads();
        s[tid] += t;
        __syncthreads();
    }
    blkcnt[b * NCHUNK + tid] = s[tid] - v;
    if (tid == NCHUNK - 1) bcnt[b] = s[NCHUNK - 1];
}

__global__ __launch_bounds__(1024) void k_bscan(int* __restrict__ bcnt) {
    __shared__ int s[1024];
    int tid = threadIdx.x;
    int v = (tid < NBUK) ? bcnt[tid] : 0;
    s[tid] = v;
    __syncthreads();
    #pragma unroll
    for (int d = 1; d < 1024; d <<= 1) {
        int t = (tid >= d) ? s[tid - d] : 0;
        __syncthreads();
        s[tid] += t;
        __syncthreads();
    }
    if (tid < NBUK) bcnt[tid] = s[tid] - v;
    if (tid == 0) bcnt[NBUK] = NE;
}

__global__ __launch_bounds__(256) void k_bucketB(const int* __restrict__ row,
                                                 const int* __restrict__ col,
                                                 const int* __restrict__ bbase,
                                                 const int* __restrict__ blkcnt,
                                                 unsigned* __restrict__ tmp) {
    __shared__ int lh[NBUK];
    const int tid = threadIdx.x;
    const int per = (NE + NCHUNK - 1) / NCHUNK;
    const int e0 = blockIdx.x * per;
    const int e1 = (e0 + per < NE) ? (e0 + per) : NE;
    for (int b = tid; b < NBUK; b += 256)
        lh[b] = bbase[b] + blkcnt[b * NCHUNK + blockIdx.x];
    __syncthreads();
    for (int e = e0 + tid; e < e1; e += 256) {
        int c = col[e], r = row[e];
        int pos = atomicAdd(&lh[c >> 7], 1);
        tmp[pos] = ((unsigned)r << 7) | (unsigned)(c & 127);
    }
}

__global__ __launch_bounds__(256) void k_build(const unsigned* __restrict__ tmp,
                                               const int* __restrict__ bbase,
                                               int* __restrict__ off,
                                               float* __restrict__ dinv,
                                               int* __restrict__ csr_row) {
    __shared__ int cnt[128], s[128], cur[128];
    const int b = blockIdx.x, tid = threadIdx.x;
    const int colBase = b << 7;
    const int nCols = (NN - colBase < 128) ? (NN - colBase) : 128;
    const int seg0 = bbase[b], seg1 = bbase[b + 1];
    if (tid < 128) cnt[tid] = 0;
    __syncthreads();
    for (int i = seg0 + tid; i < seg1; i += 256)
        atomicAdd(&cnt[tmp[i] & 127], 1);
    __syncthreads();
    if (tid < 128) s[tid] = cnt[tid];
    __syncthreads();
    #pragma unroll
    for (int d = 1; d < 128; d <<= 1) {
        int t = (tid < 128 && tid >= d) ? s[tid - d] : 0;
        __syncthreads();
        if (tid < 128) s[tid] += t;
        __syncthreads();
    }
    if (tid < nCols) {
        int exc = seg0 + s[tid] - cnt[tid];
        off[colBase + tid] = exc;
        cur[tid] = exc;
        dinv[colBase + tid] = rsqrtf((float)cnt[tid] + 1.0f);
    }
    if (b == 0 && tid == 0) off[NN] = NE;
    __syncthreads();
    for (int i = seg0 + tid; i < seg1; i += 256) {
        unsigned v = tmp[i];
        int pos = atomicAdd(&cur[v & 127u], 1);
        csr_row[pos] = (int)(v >> 7);
    }
}

// ---------------- proj GEMM (D=128): LDS-staged W, byp folded as 5th MFMA n-tile ----------------
__global__ __launch_bounds__(256) void k_gemmP(const float* __restrict__ X,
                                               const float* __restrict__ W,
                                               const float* __restrict__ bias,
                                               _Float16* __restrict__ Yh,
                                               const float* __restrict__ bypW,
                                               const float* __restrict__ bypb,
                                               float* __restrict__ bypOut,
                                               int n_nodes) {
    constexpr int D = 128, RS = D + 8, KS = D / 32;
    __shared__ _Float16 Xh[64 * RS];
    __shared__ _Float16 Wh[64 * RS];
    const int tid = threadIdx.x;
    const int n0 = blockIdx.x * 64;

    for (int i = tid; i < 64 * (D / 8); i += 256) {
        int j = i / (D / 8), d8 = (i % (D / 8)) * 8;
        const float4* wp = (const float4*)&W[j * D + d8];
        float4 w0 = wp[0], w1 = wp[1];
        h8 h = { (_Float16)w0.x, (_Float16)w0.y, (_Float16)w0.z, (_Float16)w0.w,
                 (_Float16)w1.x, (_Float16)w1.y, (_Float16)w1.z, (_Float16)w1.w };
        *(h8*)&Wh[j * RS + d8] = h;
    }
    for (int i = tid; i < 64 * (D / 8); i += 256) {
        int nl = i / (D / 8), d8 = (i % (D / 8)) * 8;
        int n = n0 + nl; if (n >= n_nodes) n = n_nodes - 1;
        const float4* xp = (const float4*)&X[(size_t)n * D + d8];
        float4 x0 = xp[0], x1 = xp[1];
        h8 h = { (_Float16)x0.x, (_Float16)x0.y, (_Float16)x0.z, (_Float16)x0.w,
                 (_Float16)x1.x, (_Float16)x1.y, (_Float16)x1.z, (_Float16)x1.w };
        *(h8*)&Xh[nl * RS + d8] = h;
    }
    __syncthreads();

    const int wid = tid >> 6, lane = tid & 63;
    const int lm = lane & 15, lq = lane >> 4;
    const int mBase = wid * 16;

    h8 bfrag[4][KS];
    #pragma unroll
    for (int t = 0; t < 4; ++t)
        #pragma unroll
        for (int s = 0; s < KS; ++s)
            bfrag[t][s] = *(const h8*)&Wh[(t * 16 + lm) * RS + s * 32 + lq * 8];

    h8 bfragB[KS];
    #pragma unroll
    for (int s = 0; s < KS; ++s) {
        if (lm < 3) {
            const float4* wp = (const float4*)&bypW[lm * D + s * 32 + lq * 8];
            float4 w0 = wp[0], w1 = wp[1];
            bfragB[s] = (h8){ (_Float16)w0.x, (_Float16)w0.y, (_Float16)w0.z, (_Float16)w0.w,
                              (_Float16)w1.x, (_Float16)w1.y, (_Float16)w1.z, (_Float16)w1.w };
        } else {
            bfragB[s] = (h8)(_Float16)0;
        }
    }

    f32x4 acc[5] = {};
    #pragma unroll
    for (int s = 0; s < KS; ++s) {
        h8 a = *(const h8*)&Xh[(mBase + lm) * RS + s * 32 + lq * 8];
        #pragma unroll
        for (int t = 0; t < 4; ++t)
            acc[t] = __builtin_amdgcn_mfma_f32_16x16x32_f16(a, bfrag[t][s], acc[t], 0, 0, 0);
        acc[4] = __builtin_amdgcn_mfma_f32_16x16x32_f16(a, bfragB[s], acc[4], 0, 0, 0);
    }

    float bb[4];
    #pragma unroll
    for (int t = 0; t < 4; ++t) bb[t] = bias[t * 16 + lm];
    float bypbv = (lm < 3) ? bypb[lm] : 0.f;
    const int nodeBase = n0 + mBase + lq * 4;
    #pragma unroll
    for (int r = 0; r < 4; ++r) {
        int node = nodeBase + r;
        if (node < n_nodes) {
            #pragma unroll
            for (int t = 0; t < 4; ++t)
                Yh[(size_t)node * 64 + t * 16 + lm] = (_Float16)(acc[t][r] + bb[t]);
            if (lm < 3)
                bypOut[node * 3 + lm] = acc[4][r] + bypbv;
        }
    }
}

// ---------------- conv GEMM (D=64): fp16 out + fp8 e4m3 message copy ----------------
__global__ __launch_bounds__(256) void k_gemmC(const _Float16* __restrict__ Xhg,
                                               const float* __restrict__ W,
                                               const float* __restrict__ dinv,
                                               _Float16* __restrict__ Yh,
                                               unsigned char* __restrict__ Y8,
                                               int n_nodes) {
    constexpr int D = 64, RS = D + 8, KS = D / 32;
    __shared__ _Float16 Xh[64 * RS];
    __shared__ _Float16 Wh[64 * RS];
    const int tid = threadIdx.x;
    const int n0 = blockIdx.x * 64;

    for (int i = tid; i < 64 * (D / 8); i += 256) {
        int j = i / (D / 8), d8 = (i % (D / 8)) * 8;
        const float4* wp = (const float4*)&W[j * D + d8];
        float4 w0 = wp[0], w1 = wp[1];
        h8 h = { (_Float16)w0.x, (_Float16)w0.y, (_Float16)w0.z, (_Float16)w0.w,
                 (_Float16)w1.x, (_Float16)w1.y, (_Float16)w1.z, (_Float16)w1.w };
        *(h8*)&Wh[j * RS + d8] = h;
    }
    for (int i = tid; i < 64 * (D / 8); i += 256) {
        int nl = i / (D / 8), d8 = (i % (D / 8)) * 8;
        int n = n0 + nl; if (n >= n_nodes) n = n_nodes - 1;
        *(h8*)&Xh[nl * RS + d8] = *(const h8*)&Xhg[(size_t)n * D + d8];
    }
    __syncthreads();

    const int wid = tid >> 6, lane = tid & 63;
    const int lm = lane & 15, lq = lane >> 4;
    const int mBase = wid * 16;

    h8 bfrag[4][KS];
    #pragma unroll
    for (int t = 0; t < 4; ++t)
        #pragma unroll
        for (int s = 0; s < KS; ++s)
            bfrag[t][s] = *(const h8*)&Wh[(t * 16 + lm) * RS + s * 32 + lq * 8];

    f32x4 acc[4] = {};
    #pragma unroll
    for (int s = 0; s < KS; ++s) {
        h8 a = *(const h8*)&Xh[(mBase + lm) * RS + s * 32 + lq * 8];
        #pragma unroll
        for (int t = 0; t < 4; ++t)
            acc[t] = __builtin_amdgcn_mfma_f32_16x16x32_f16(a, bfrag[t][s], acc[t], 0, 0, 0);
    }

    const int nodeBase = n0 + mBase + lq * 4;
    #pragma unroll
    for (int r = 0; r < 4; ++r) {
        int node = nodeBase + r;
        if (node < n_nodes) {
            float sdv = dinv[node];
            #pragma unroll
            for (int t = 0; t < 4; ++t) {
                float v = acc[t][r] * sdv;
                Yh[(size_t)node * 64 + t * 16 + lm] = (_Float16)v;
                int pk = __builtin_amdgcn_cvt_pk_fp8_f32(v, v, 0, false);
                Y8[(size_t)node * 64 + t * 16 + lm] = (unsigned char)(pk & 0xff);
            }
        }
    }
}

// ---------------- pull-aggregation: fp8 edge messages, fp16 self term, fp32 acc ----------------
template<bool RES, bool HEAD>
__global__ __launch_bounds__(256) void k_gather(const _Float16* __restrict__ hBh,
                                                const unsigned char* __restrict__ hB8,
                                                const float* __restrict__ dinv,
                                                const int* __restrict__ off,
                                                const int* __restrict__ csr_row,
                                                const float* __restrict__ convb,
                                                const float* __restrict__ bng,
                                                const float* __restrict__ bnb,
                                                _Float16* __restrict__ hA,
                                                const float* __restrict__ byp,
                                                const float* __restrict__ headW,
                                                const float* __restrict__ headb,
                                                float* __restrict__ out) {
    __shared__ float HWs[HEAD ? 204 : 1];
    const int tid = threadIdx.x;
    if constexpr (HEAD) {
        for (int i = tid; i < 204; i += 256)
            HWs[i] = (i < 201) ? headW[i] : headb[i - 201];
        __syncthreads();
    }
    const int wid = tid >> 6, lane = tid & 63;
    const int n = blockIdx.x * 32 + wid * 8 + (lane >> 3);   // grid = NN/32 exactly
    const int oct = lane & 7;
    const int f0 = oct * 8;

    const int e0 = off[n], eEnd = off[n + 1];
    const int deg = eEnd - e0;
    int m = deg;
    #pragma unroll
    for (int mask = 8; mask < 64; mask <<= 1) {
        int o = __shfl_xor(m, mask, 64);
        m = (o > m) ? o : m;
    }

    float acc[8];
    {   // self-loop term (fp16, exact)
        h8 s = *(const h8*)(hBh + ((size_t)n << 6) + f0);
        #pragma unroll
        for (int j = 0; j < 8; ++j) acc[j] = (float)s[j];
    }
    const uint2* rows8 = (const uint2*)hB8;   // 8 uint2 per node row
    for (int it = 0; it < m; it += 4) {
        bool v0 = it < deg, v1 = it + 1 < deg, v2 = it + 2 < deg, v3 = it + 3 < deg;
        int i0 = e0 + it;
        int r0 = csr_row[v0 ? i0 : 0];
        int r1 = csr_row[v1 ? i0 + 1 : 0];
        int r2 = csr_row[v2 ? i0 + 2 : 0];
        int r3 = csr_row[v3 ? i0 + 3 : 0];
        uint2 w0 = rows8[(size_t)r0 * 8 + oct];
        uint2 w1 = rows8[(size_t)r1 * 8 + oct];
        uint2 w2 = rows8[(size_t)r2 * 8 + oct];
        uint2 w3 = rows8[(size_t)r3 * 8 + oct];
        if (!v0) { w0.x = 0; w0.y = 0; }
        if (!v1) { w1.x = 0; w1.y = 0; }
        if (!v2) { w2.x = 0; w2.y = 0; }
        if (!v3) { w3.x = 0; w3.y = 0; }
        #pragma unroll
        for (int q = 0; q < 4; ++q) {
            uint2 w = (q == 0) ? w0 : (q == 1) ? w1 : (q == 2) ? w2 : w3;
            f32x2 p0 = __builtin_amdgcn_cvt_pk_f32_fp8(w.x, false);
            f32x2 p1 = __builtin_amdgcn_cvt_pk_f32_fp8(w.x, true);
            f32x2 p2 = __builtin_amdgcn_cvt_pk_f32_fp8(w.y, false);
            f32x2 p3 = __builtin_amdgcn_cvt_pk_f32_fp8(w.y, true);
            acc[0] += p0.x; acc[1] += p0.y; acc[2] += p1.x; acc[3] += p1.y;
            acc[4] += p2.x; acc[5] += p2.y; acc[6] += p3.x; acc[7] += p3.y;
        }
    }

    const float dv = dinv[n];
    const float bnscale = rsqrtf(1.0f + 1e-5f);
    const float4 cb0 = *(const float4*)&convb[f0], cb1 = *(const float4*)&convb[f0 + 4];
    const float4 g0  = *(const float4*)&bng[f0],  g1  = *(const float4*)&bng[f0 + 4];
    const float4 b0_ = *(const float4*)&bnb[f0],  b1_ = *(const float4*)&bnb[f0 + 4];
    const float cb[8] = { cb0.x, cb0.y, cb0.z, cb0.w, cb1.x, cb1.y, cb1.z, cb1.w };
    const float gg[8] = { g0.x, g0.y, g0.z, g0.w, g1.x, g1.y, g1.z, g1.w };
    const float bb[8] = { b0_.x, b0_.y, b0_.z, b0_.w, b1_.x, b1_.y, b1_.z, b1_.w };
    float v[8];
    #pragma unroll
    for (int j = 0; j < 8; ++j)
        v[j] = fmaxf((acc[j] * dv + cb[j]) * (gg[j] * bnscale) + bb[j], 0.0f);

    if constexpr (!HEAD) {
        size_t o = ((size_t)n << 6) + f0;
        if constexpr (RES) {
            h8 old = *(const h8*)&hA[o];
            #pragma unroll
            for (int j = 0; j < 8; ++j) v[j] += (float)old[j];
        }
        h8 res = { (_Float16)v[0], (_Float16)v[1], (_Float16)v[2], (_Float16)v[3],
                   (_Float16)v[4], (_Float16)v[5], (_Float16)v[6], (_Float16)v[7] };
        *(h8*)&hA[o] = res;
    } else {
        float p[3];
        #pragma unroll
        for (int o = 0; o < 3; ++o) {
            float t = 0.f;
            #pragma unroll
            for (int j = 0; j < 8; ++j) t += v[j] * HWs[o * 67 + f0 + j];
            p[o] = t;
        }
        #pragma unroll
        for (int mask = 1; mask < 8; mask <<= 1) {
            #pragma unroll
            for (int o = 0; o < 3; ++o) p[o] += __shfl_xor(p[o], mask, 64);
        }
        if (oct == 0) {
            float by0 = byp[n * 3], by1 = byp[n * 3 + 1], by2 = byp[n * 3 + 2];
            #pragma unroll
            for (int o = 0; o < 3; ++o)
                p[o] += by0 * HWs[o * 67 + 64] + by1 * HWs[o * 67 + 65] + by2 * HWs[o * 67 + 66]
                      + HWs[201 + o];
            float kappa = fminf(fmaxf(p[0] * 5.0f + 2.5f, 0.2f), 10.0f);
            float tau   = fminf(fmaxf(p[2] + 0.5f, 0.05f), 2.0f);
            out[(size_t)n * 3]     = kappa;
            out[(size_t)n * 3 + 1] = p[1];
            out[(size_t)n * 3 + 2] = tau;
        }
    }
}

extern "C" void kernel_launch(void* const* d_in, const int* in_sizes, int n_in,
                              void* d_out, int out_size, void* d_ws, size_t ws_size,
                              hipStream_t stream) {
    const float* x     = (const float*)d_in[0];
    const int*   ei    = (const int*)d_in[1];
    const int*   row   = ei;
    const int*   col   = ei + NE;
    const float* projW = (const float*)d_in[2];
    const float* projb = (const float*)d_in[3];
    const float* convW[3] = { (const float*)d_in[4], (const float*)d_in[8],  (const float*)d_in[12] };
    const float* convb[3] = { (const float*)d_in[5], (const float*)d_in[9],  (const float*)d_in[13] };
    const float* bng[3]   = { (const float*)d_in[6], (const float*)d_in[10], (const float*)d_in[14] };
    const float* bnb[3]   = { (const float*)d_in[7], (const float*)d_in[11], (const float*)d_in[15] };
    const float* bypW  = (const float*)d_in[16];
    const float* bypb  = (const float*)d_in[17];
    const float* headW = (const float*)d_in[18];
    const float* headb = (const float*)d_in[19];
    float* out = (float*)d_out;

    float*    ws   = (float*)d_ws;
    float*    dinv = ws;                                   // 102400 floats
    _Float16* hAh  = (_Float16*)(ws + 102400);             // NN*64 fp16
    _Float16* hBh  = hAh + (size_t)NN * 64;                // NN*64 fp16
    float*    byp  = (float*)(hBh + (size_t)NN * 64);      // NN*3 (+pad)
    int*      off     = (int*)(byp + 300032);              // NN+1 (pad 100096)
    int*      csr_row = off + 100096;                      // NE
    int*      bcnt    = csr_row + NE;                      // NBUK+1 (pad 784)
    int*      blkcnt  = bcnt + 784;                        // NBUK*NCHUNK = 100096
    unsigned char* hB8 = (unsigned char*)(blkcnt + 100096);// NN*64 bytes fp8
    unsigned* tmp     = (unsigned*)hAh;                    // aliases hAh (consumed before proj)

    // deterministic bucketed CSR build (+dinv +off) — zero global atomics
    k_bucketA<<<NCHUNK, 256, 0, stream>>>(col, blkcnt);
    k_colscan<<<NBUK, 128, 0, stream>>>(blkcnt, bcnt);
    k_bscan<<<1, 1024, 0, stream>>>(bcnt);
    k_bucketB<<<NCHUNK, 256, 0, stream>>>(row, col, bcnt, blkcnt, tmp);
    k_build<<<NBUK, 256, 0, stream>>>(tmp, bcnt, off, dinv, csr_row);

    // proj: hAh = fp16(x @ projW.T + projb), byp = x @ bypW.T + bypb (fused MFMA tile)
    k_gemmP<<<(NN + 63) / 64, 256, 0, stream>>>(x, projW, projb, hAh, bypW, bypb, byp, NN);

    for (int l = 0; l < 3; l++) {
        // hBh/hB8 = fp16/fp8((hAh @ convW.T) * dinv)
        k_gemmC<<<(NN + 63) / 64, 256, 0, stream>>>(hAh, convW[l], dinv, hBh, hB8, NN);
        if (l < 2)
            k_gather<true, false><<<NN / 32, 256, 0, stream>>>(
                hBh, hB8, dinv, off, csr_row, convb[l], bng[l], bnb[l], hAh,
                nullptr, nullptr, nullptr, nullptr);
        else
            k_gather<false, true><<<NN / 32, 256, 0, stream>>>(
                hBh, hB8, dinv, off, csr_row, convb[l], bng[l], bnb[l], nullptr,
                byp, headW, headb, out);
    }
}

// Round 19
// 262.374 us; speedup vs baseline: 1.2018x; 1.0427x over previous
//
#include <hip/hip_runtime.h>
#include <hip/hip_fp16.h>

#define NN 100000
#define NE 1200000
#define NBUK ((NN + 127) / 128)   // 782
#define NCHUNK 128                // chunks in bucket passes

typedef _Float16 h8 __attribute__((ext_vector_type(8)));
typedef float f32x4 __attribute__((ext_vector_type(4)));
typedef float f32x2 __attribute__((ext_vector_type(2)));

// ---------------- deterministic two-phase bucketed CSR build ----------------
__global__ __launch_bounds__(256) void k_bucketA(const int* __restrict__ col,
                                                 int* __restrict__ blkcnt) {
    __shared__ int lh[NBUK];
    const int tid = threadIdx.x;
    const int per = (NE + NCHUNK - 1) / NCHUNK;
    const int e0 = blockIdx.x * per;
    const int e1 = (e0 + per < NE) ? (e0 + per) : NE;
    for (int i = tid; i < NBUK; i += 256) lh[i] = 0;
    __syncthreads();
    for (int e = e0 + tid; e < e1; e += 256)
        atomicAdd(&lh[col[e] >> 7], 1);
    __syncthreads();
    for (int b = tid; b < NBUK; b += 256)
        blkcnt[b * NCHUNK + blockIdx.x] = lh[b];
}

__global__ __launch_bounds__(128) void k_colscan(int* __restrict__ blkcnt, int* __restrict__ bcnt) {
    __shared__ int s[NCHUNK];
    const int b = blockIdx.x, tid = threadIdx.x;
    int v = blkcnt[b * NCHUNK + tid];
    s[tid] = v;
    __syncthreads();
    #pragma unroll
    for (int d = 1; d < NCHUNK; d <<= 1) {
        int t = (tid >= d) ? s[tid - d] : 0;
        __syncthreads();
        s[tid] += t;
        __syncthreads();
    }
    blkcnt[b * NCHUNK + tid] = s[tid] - v;
    if (tid == NCHUNK - 1) bcnt[b] = s[NCHUNK - 1];
}

__global__ __launch_bounds__(1024) void k_bscan(int* __restrict__ bcnt) {
    __shared__ int s[1024];
    int tid = threadIdx.x;
    int v = (tid < NBUK) ? bcnt[tid] : 0;
    s[tid] = v;
    __syncthreads();
    #pragma unroll
    for (int d = 1; d < 1024; d <<= 1) {
        int t = (tid >= d) ? s[tid - d] : 0;
        __syncthreads();
        s[tid] += t;
        __syncthreads();
    }
    if (tid < NBUK) bcnt[tid] = s[tid] - v;
    if (tid == 0) bcnt[NBUK] = NE;
}

__global__ __launch_bounds__(256) void k_bucketB(const int* __restrict__ row,
                                                 const int* __restrict__ col,
                                                 const int* __restrict__ bbase,
                                                 const int* __restrict__ blkcnt,
                                                 unsigned* __restrict__ tmp) {
    __shared__ int lh[NBUK];
    const int tid = threadIdx.x;
    const int per = (NE + NCHUNK - 1) / NCHUNK;
    const int e0 = blockIdx.x * per;
    const int e1 = (e0 + per < NE) ? (e0 + per) : NE;
    for (int b = tid; b < NBUK; b += 256)
        lh[b] = bbase[b] + blkcnt[b * NCHUNK + blockIdx.x];
    __syncthreads();
    for (int e = e0 + tid; e < e1; e += 256) {
        int c = col[e], r = row[e];
        int pos = atomicAdd(&lh[c >> 7], 1);
        tmp[pos] = ((unsigned)r << 7) | (unsigned)(c & 127);
    }
}

__global__ __launch_bounds__(256) void k_build(const unsigned* __restrict__ tmp,
                                               const int* __restrict__ bbase,
                                               int* __restrict__ off,
                                               float* __restrict__ dinv,
                                               int* __restrict__ csr_row) {
    __shared__ int cnt[128], s[128], cur[128];
    const int b = blockIdx.x, tid = threadIdx.x;
    const int colBase = b << 7;
    const int nCols = (NN - colBase < 128) ? (NN - colBase) : 128;
    const int seg0 = bbase[b], seg1 = bbase[b + 1];
    if (tid < 128) cnt[tid] = 0;
    __syncthreads();
    for (int i = seg0 + tid; i < seg1; i += 256)
        atomicAdd(&cnt[tmp[i] & 127], 1);
    __syncthreads();
    if (tid < 128) s[tid] = cnt[tid];
    __syncthreads();
    #pragma unroll
    for (int d = 1; d < 128; d <<= 1) {
        int t = (tid < 128 && tid >= d) ? s[tid - d] : 0;
        __syncthreads();
        if (tid < 128) s[tid] += t;
        __syncthreads();
    }
    if (tid < nCols) {
        int exc = seg0 + s[tid] - cnt[tid];
        off[colBase + tid] = exc;
        cur[tid] = exc;
        dinv[colBase + tid] = rsqrtf((float)cnt[tid] + 1.0f);
    }
    if (b == 0 && tid == 0) off[NN] = NE;
    __syncthreads();
    for (int i = seg0 + tid; i < seg1; i += 256) {
        unsigned v = tmp[i];
        int pos = atomicAdd(&cur[v & 127u], 1);
        csr_row[pos] = (int)(v >> 7);
    }
}

// ---------------- proj GEMM (D=128): LDS-staged W, byp folded as 5th MFMA n-tile ----------------
__global__ __launch_bounds__(256) void k_gemmP(const float* __restrict__ X,
                                               const float* __restrict__ W,
                                               const float* __restrict__ bias,
                                               _Float16* __restrict__ Yh,
                                               const float* __restrict__ bypW,
                                               const float* __restrict__ bypb,
                                               float* __restrict__ bypOut,
                                               int n_nodes) {
    constexpr int D = 128, RS = D + 8, KS = D / 32;
    __shared__ _Float16 Xh[64 * RS];
    __shared__ _Float16 Wh[64 * RS];
    const int tid = threadIdx.x;
    const int n0 = blockIdx.x * 64;

    for (int i = tid; i < 64 * (D / 8); i += 256) {
        int j = i / (D / 8), d8 = (i % (D / 8)) * 8;
        const float4* wp = (const float4*)&W[j * D + d8];
        float4 w0 = wp[0], w1 = wp[1];
        h8 h = { (_Float16)w0.x, (_Float16)w0.y, (_Float16)w0.z, (_Float16)w0.w,
                 (_Float16)w1.x, (_Float16)w1.y, (_Float16)w1.z, (_Float16)w1.w };
        *(h8*)&Wh[j * RS + d8] = h;
    }
    for (int i = tid; i < 64 * (D / 8); i += 256) {
        int nl = i / (D / 8), d8 = (i % (D / 8)) * 8;
        int n = n0 + nl; if (n >= n_nodes) n = n_nodes - 1;
        const float4* xp = (const float4*)&X[(size_t)n * D + d8];
        float4 x0 = xp[0], x1 = xp[1];
        h8 h = { (_Float16)x0.x, (_Float16)x0.y, (_Float16)x0.z, (_Float16)x0.w,
                 (_Float16)x1.x, (_Float16)x1.y, (_Float16)x1.z, (_Float16)x1.w };
        *(h8*)&Xh[nl * RS + d8] = h;
    }
    __syncthreads();

    const int wid = tid >> 6, lane = tid & 63;
    const int lm = lane & 15, lq = lane >> 4;
    const int mBase = wid * 16;

    h8 bfrag[4][KS];
    #pragma unroll
    for (int t = 0; t < 4; ++t)
        #pragma unroll
        for (int s = 0; s < KS; ++s)
            bfrag[t][s] = *(const h8*)&Wh[(t * 16 + lm) * RS + s * 32 + lq * 8];

    h8 bfragB[KS];
    #pragma unroll
    for (int s = 0; s < KS; ++s) {
        if (lm < 3) {
            const float4* wp = (const float4*)&bypW[lm * D + s * 32 + lq * 8];
            float4 w0 = wp[0], w1 = wp[1];
            bfragB[s] = (h8){ (_Float16)w0.x, (_Float16)w0.y, (_Float16)w0.z, (_Float16)w0.w,
                              (_Float16)w1.x, (_Float16)w1.y, (_Float16)w1.z, (_Float16)w1.w };
        } else {
            bfragB[s] = (h8)(_Float16)0;
        }
    }

    f32x4 acc[5] = {};
    #pragma unroll
    for (int s = 0; s < KS; ++s) {
        h8 a = *(const h8*)&Xh[(mBase + lm) * RS + s * 32 + lq * 8];
        #pragma unroll
        for (int t = 0; t < 4; ++t)
            acc[t] = __builtin_amdgcn_mfma_f32_16x16x32_f16(a, bfrag[t][s], acc[t], 0, 0, 0);
        acc[4] = __builtin_amdgcn_mfma_f32_16x16x32_f16(a, bfragB[s], acc[4], 0, 0, 0);
    }

    float bb[4];
    #pragma unroll
    for (int t = 0; t < 4; ++t) bb[t] = bias[t * 16 + lm];
    float bypbv = (lm < 3) ? bypb[lm] : 0.f;
    const int nodeBase = n0 + mBase + lq * 4;
    #pragma unroll
    for (int r = 0; r < 4; ++r) {
        int node = nodeBase + r;
        if (node < n_nodes) {
            #pragma unroll
            for (int t = 0; t < 4; ++t)
                Yh[(size_t)node * 64 + t * 16 + lm] = (_Float16)(acc[t][r] + bb[t]);
            if (lm < 3)
                bypOut[node * 3 + lm] = acc[4][r] + bypbv;
        }
    }
}

// ---------------- conv GEMM (D=64): fp8 e4m3 message output only ----------------
__global__ __launch_bounds__(256) void k_gemmC(const _Float16* __restrict__ Xhg,
                                               const float* __restrict__ W,
                                               const float* __restrict__ dinv,
                                               unsigned char* __restrict__ Y8,
                                               int n_nodes) {
    constexpr int D = 64, RS = D + 8, KS = D / 32;
    __shared__ _Float16 Xh[64 * RS];
    __shared__ _Float16 Wh[64 * RS];
    const int tid = threadIdx.x;
    const int n0 = blockIdx.x * 64;

    for (int i = tid; i < 64 * (D / 8); i += 256) {
        int j = i / (D / 8), d8 = (i % (D / 8)) * 8;
        const float4* wp = (const float4*)&W[j * D + d8];
        float4 w0 = wp[0], w1 = wp[1];
        h8 h = { (_Float16)w0.x, (_Float16)w0.y, (_Float16)w0.z, (_Float16)w0.w,
                 (_Float16)w1.x, (_Float16)w1.y, (_Float16)w1.z, (_Float16)w1.w };
        *(h8*)&Wh[j * RS + d8] = h;
    }
    for (int i = tid; i < 64 * (D / 8); i += 256) {
        int nl = i / (D / 8), d8 = (i % (D / 8)) * 8;
        int n = n0 + nl; if (n >= n_nodes) n = n_nodes - 1;
        *(h8*)&Xh[nl * RS + d8] = *(const h8*)&Xhg[(size_t)n * D + d8];
    }
    __syncthreads();

    const int wid = tid >> 6, lane = tid & 63;
    const int lm = lane & 15, lq = lane >> 4;
    const int mBase = wid * 16;

    h8 bfrag[4][KS];
    #pragma unroll
    for (int t = 0; t < 4; ++t)
        #pragma unroll
        for (int s = 0; s < KS; ++s)
            bfrag[t][s] = *(const h8*)&Wh[(t * 16 + lm) * RS + s * 32 + lq * 8];

    f32x4 acc[4] = {};
    #pragma unroll
    for (int s = 0; s < KS; ++s) {
        h8 a = *(const h8*)&Xh[(mBase + lm) * RS + s * 32 + lq * 8];
        #pragma unroll
        for (int t = 0; t < 4; ++t)
            acc[t] = __builtin_amdgcn_mfma_f32_16x16x32_f16(a, bfrag[t][s], acc[t], 0, 0, 0);
    }

    const int nodeBase = n0 + mBase + lq * 4;
    #pragma unroll
    for (int r = 0; r < 4; ++r) {
        int node = nodeBase + r;
        if (node < n_nodes) {
            float sdv = dinv[node];
            #pragma unroll
            for (int t = 0; t < 4; ++t) {
                float v = acc[t][r] * sdv;
                int pk = __builtin_amdgcn_cvt_pk_fp8_f32(v, v, 0, false);
                Y8[(size_t)node * 64 + t * 16 + lm] = (unsigned char)(pk & 0xff);
            }
        }
    }
}

// ---------------- pull-aggregation: fp8 messages (incl. self), fp32 acc, 8-wide MLP ----------------
template<bool RES, bool HEAD>
__global__ __launch_bounds__(256) void k_gather(const unsigned char* __restrict__ hB8,
                                                const float* __restrict__ dinv,
                                                const int* __restrict__ off,
                                                const int* __restrict__ csr_row,
                                                const float* __restrict__ convb,
                                                const float* __restrict__ bng,
                                                const float* __restrict__ bnb,
                                                _Float16* __restrict__ hA,
                                                const float* __restrict__ byp,
                                                const float* __restrict__ headW,
                                                const float* __restrict__ headb,
                                                float* __restrict__ out) {
    __shared__ float HWs[HEAD ? 204 : 1];
    const int tid = threadIdx.x;
    if constexpr (HEAD) {
        for (int i = tid; i < 204; i += 256)
            HWs[i] = (i < 201) ? headW[i] : headb[i - 201];
        __syncthreads();
    }
    const int wid = tid >> 6, lane = tid & 63;
    const int n = blockIdx.x * 32 + wid * 8 + (lane >> 3);   // grid = NN/32 exactly
    const int oct = lane & 7;
    const int f0 = oct * 8;

    const int e0 = off[n], eEnd = off[n + 1];
    const int deg = eEnd - e0;
    int m = deg;
    #pragma unroll
    for (int mask = 8; mask < 64; mask <<= 1) {
        int o = __shfl_xor(m, mask, 64);
        m = (o > m) ? o : m;
    }

    const uint2* rows8 = (const uint2*)hB8;   // 8 uint2 per node row
    float acc[8] = {0, 0, 0, 0, 0, 0, 0, 0};
    uint2 selfw = rows8[(size_t)n * 8 + oct];
    {
        f32x2 p0 = __builtin_amdgcn_cvt_pk_f32_fp8(selfw.x, false);
        f32x2 p1 = __builtin_amdgcn_cvt_pk_f32_fp8(selfw.x, true);
        f32x2 p2 = __builtin_amdgcn_cvt_pk_f32_fp8(selfw.y, false);
        f32x2 p3 = __builtin_amdgcn_cvt_pk_f32_fp8(selfw.y, true);
        acc[0] += p0.x; acc[1] += p0.y; acc[2] += p1.x; acc[3] += p1.y;
        acc[4] += p2.x; acc[5] += p2.y; acc[6] += p3.x; acc[7] += p3.y;
    }
    for (int it = 0; it < m; it += 8) {
        uint2 w[8];
        #pragma unroll
        for (int q = 0; q < 8; ++q) {
            bool vq = it + q < deg;
            int rq = csr_row[vq ? e0 + it + q : 0];
            w[q] = rows8[(size_t)rq * 8 + oct];
            if (!vq) { w[q].x = 0; w[q].y = 0; }
        }
        #pragma unroll
        for (int q = 0; q < 8; ++q) {
            f32x2 p0 = __builtin_amdgcn_cvt_pk_f32_fp8(w[q].x, false);
            f32x2 p1 = __builtin_amdgcn_cvt_pk_f32_fp8(w[q].x, true);
            f32x2 p2 = __builtin_amdgcn_cvt_pk_f32_fp8(w[q].y, false);
            f32x2 p3 = __builtin_amdgcn_cvt_pk_f32_fp8(w[q].y, true);
            acc[0] += p0.x; acc[1] += p0.y; acc[2] += p1.x; acc[3] += p1.y;
            acc[4] += p2.x; acc[5] += p2.y; acc[6] += p3.x; acc[7] += p3.y;
        }
    }

    const float dv = dinv[n];
    const float bnscale = rsqrtf(1.0f + 1e-5f);
    const float4 cb0 = *(const float4*)&convb[f0], cb1 = *(const float4*)&convb[f0 + 4];
    const float4 g0  = *(const float4*)&bng[f0],  g1  = *(const float4*)&bng[f0 + 4];
    const float4 b0_ = *(const float4*)&bnb[f0],  b1_ = *(const float4*)&bnb[f0 + 4];
    const float cb[8] = { cb0.x, cb0.y, cb0.z, cb0.w, cb1.x, cb1.y, cb1.z, cb1.w };
    const float gg[8] = { g0.x, g0.y, g0.z, g0.w, g1.x, g1.y, g1.z, g1.w };
    const float bb[8] = { b0_.x, b0_.y, b0_.z, b0_.w, b1_.x, b1_.y, b1_.z, b1_.w };
    float v[8];
    #pragma unroll
    for (int j = 0; j < 8; ++j)
        v[j] = fmaxf((acc[j] * dv + cb[j]) * (gg[j] * bnscale) + bb[j], 0.0f);

    if constexpr (!HEAD) {
        size_t o = ((size_t)n << 6) + f0;
        if constexpr (RES) {
            h8 old = *(const h8*)&hA[o];
            #pragma unroll
            for (int j = 0; j < 8; ++j) v[j] += (float)old[j];
        }
        h8 res = { (_Float16)v[0], (_Float16)v[1], (_Float16)v[2], (_Float16)v[3],
                   (_Float16)v[4], (_Float16)v[5], (_Float16)v[6], (_Float16)v[7] };
        *(h8*)&hA[o] = res;
    } else {
        float p[3];
        #pragma unroll
        for (int o = 0; o < 3; ++o) {
            float t = 0.f;
            #pragma unroll
            for (int j = 0; j < 8; ++j) t += v[j] * HWs[o * 67 + f0 + j];
            p[o] = t;
        }
        #pragma unroll
        for (int mask = 1; mask < 8; mask <<= 1) {
            #pragma unroll
            for (int o = 0; o < 3; ++o) p[o] += __shfl_xor(p[o], mask, 64);
        }
        if (oct == 0) {
            float by0 = byp[n * 3], by1 = byp[n * 3 + 1], by2 = byp[n * 3 + 2];
            #pragma unroll
            for (int o = 0; o < 3; ++o)
                p[o] += by0 * HWs[o * 67 + 64] + by1 * HWs[o * 67 + 65] + by2 * HWs[o * 67 + 66]
                      + HWs[201 + o];
            float kappa = fminf(fmaxf(p[0] * 5.0f + 2.5f, 0.2f), 10.0f);
            float tau   = fminf(fmaxf(p[2] + 0.5f, 0.05f), 2.0f);
            out[(size_t)n * 3]     = kappa;
            out[(size_t)n * 3 + 1] = p[1];
            out[(size_t)n * 3 + 2] = tau;
        }
    }
}

extern "C" void kernel_launch(void* const* d_in, const int* in_sizes, int n_in,
                              void* d_out, int out_size, void* d_ws, size_t ws_size,
                              hipStream_t stream) {
    const float* x     = (const float*)d_in[0];
    const int*   ei    = (const int*)d_in[1];
    const int*   row   = ei;
    const int*   col   = ei + NE;
    const float* projW = (const float*)d_in[2];
    const float* projb = (const float*)d_in[3];
    const float* convW[3] = { (const float*)d_in[4], (const float*)d_in[8],  (const float*)d_in[12] };
    const float* convb[3] = { (const float*)d_in[5], (const float*)d_in[9],  (const float*)d_in[13] };
    const float* bng[3]   = { (const float*)d_in[6], (const float*)d_in[10], (const float*)d_in[14] };
    const float* bnb[3]   = { (const float*)d_in[7], (const float*)d_in[11], (const float*)d_in[15] };
    const float* bypW  = (const float*)d_in[16];
    const float* bypb  = (const float*)d_in[17];
    const float* headW = (const float*)d_in[18];
    const float* headb = (const float*)d_in[19];
    float* out = (float*)d_out;

    float*    ws   = (float*)d_ws;
    float*    dinv = ws;                                   // 102400 floats
    _Float16* hAh  = (_Float16*)(ws + 102400);             // NN*64 fp16
    unsigned char* hB8 = (unsigned char*)(hAh + (size_t)NN * 64);  // NN*64 bytes fp8
    float*    byp  = (float*)(hB8 + (size_t)NN * 64);      // NN*3 (+pad 300032)
    int*      off     = (int*)(byp + 300032);              // NN+1 (pad 100096)
    int*      csr_row = off + 100096;                      // NE
    int*      bcnt    = csr_row + NE;                      // NBUK+1 (pad 784)
    int*      blkcnt  = bcnt + 784;                        // NBUK*NCHUNK = 100096
    unsigned* tmp     = (unsigned*)hAh;                    // aliases hAh (consumed before proj)

    // deterministic bucketed CSR build (+dinv +off) — zero global atomics
    k_bucketA<<<NCHUNK, 256, 0, stream>>>(col, blkcnt);
    k_colscan<<<NBUK, 128, 0, stream>>>(blkcnt, bcnt);
    k_bscan<<<1, 1024, 0, stream>>>(bcnt);
    k_bucketB<<<NCHUNK, 256, 0, stream>>>(row, col, bcnt, blkcnt, tmp);
    k_build<<<NBUK, 256, 0, stream>>>(tmp, bcnt, off, dinv, csr_row);

    // proj: hAh = fp16(x @ projW.T + projb), byp = x @ bypW.T + bypb (fused MFMA tile)
    k_gemmP<<<(NN + 63) / 64, 256, 0, stream>>>(x, projW, projb, hAh, bypW, bypb, byp, NN);

    for (int l = 0; l < 3; l++) {
        // hB8 = fp8((hAh @ convW.T) * dinv)
        k_gemmC<<<(NN + 63) / 64, 256, 0, stream>>>(hAh, convW[l], dinv, hB8, NN);
        if (l < 2)
            k_gather<true, false><<<NN / 32, 256, 0, stream>>>(
                hB8, dinv, off, csr_row, convb[l], bng[l], bnb[l], hAh,
                nullptr, nullptr, nullptr, nullptr);
        else
            k_gather<false, true><<<NN / 32, 256, 0, stream>>>(
                hB8, dinv, off, csr_row, convb[l], bng[l], bnb[l], nullptr,
                byp, headW, headb, out);
    }
}

// Round 20
// 259.742 us; speedup vs baseline: 1.2140x; 1.0101x over previous
//
#include <hip/hip_runtime.h>
#include <hip/hip_fp16.h>

#define NN 100000
#define NE 1200000
#define NBUK ((NN + 127) / 128)   // 782
#define NCHUNK 128                // chunks in bucket passes

typedef _Float16 h8 __attribute__((ext_vector_type(8)));
typedef float f32x4 __attribute__((ext_vector_type(4)));
typedef float f32x2 __attribute__((ext_vector_type(2)));

// ---------------- deterministic two-phase bucketed CSR build ----------------
__global__ __launch_bounds__(256) void k_bucketA(const int* __restrict__ col,
                                                 int* __restrict__ blkcnt) {
    __shared__ int lh[NBUK];
    const int tid = threadIdx.x;
    const int per = (NE + NCHUNK - 1) / NCHUNK;
    const int e0 = blockIdx.x * per;
    const int e1 = (e0 + per < NE) ? (e0 + per) : NE;
    for (int i = tid; i < NBUK; i += 256) lh[i] = 0;
    __syncthreads();
    for (int e = e0 + tid; e < e1; e += 256)
        atomicAdd(&lh[col[e] >> 7], 1);
    __syncthreads();
    for (int b = tid; b < NBUK; b += 256)
        blkcnt[b * NCHUNK + blockIdx.x] = lh[b];
}

__global__ __launch_bounds__(128) void k_colscan(int* __restrict__ blkcnt, int* __restrict__ bcnt) {
    __shared__ int s[NCHUNK];
    const int b = blockIdx.x, tid = threadIdx.x;
    int v = blkcnt[b * NCHUNK + tid];
    s[tid] = v;
    __syncthreads();
    #pragma unroll
    for (int d = 1; d < NCHUNK; d <<= 1) {
        int t = (tid >= d) ? s[tid - d] : 0;
        __syncthreads();
        s[tid] += t;
        __syncthreads();
    }
    blkcnt[b * NCHUNK + tid] = s[tid] - v;
    if (tid == NCHUNK - 1) bcnt[b] = s[NCHUNK - 1];
}

__global__ __launch_bounds__(1024) void k_bscan(int* __restrict__ bcnt) {
    __shared__ int s[1024];
    int tid = threadIdx.x;
    int v = (tid < NBUK) ? bcnt[tid] : 0;
    s[tid] = v;
    __syncthreads();
    #pragma unroll
    for (int d = 1; d < 1024; d <<= 1) {
        int t = (tid >= d) ? s[tid - d] : 0;
        __syncthreads();
        s[tid] += t;
        __syncthreads();
    }
    if (tid < NBUK) bcnt[tid] = s[tid] - v;
    if (tid == 0) bcnt[NBUK] = NE;
}

__global__ __launch_bounds__(256) void k_bucketB(const int* __restrict__ row,
                                                 const int* __restrict__ col,
                                                 const int* __restrict__ bbase,
                                                 const int* __restrict__ blkcnt,
                                                 unsigned* __restrict__ tmp) {
    __shared__ int lh[NBUK];
    const int tid = threadIdx.x;
    const int per = (NE + NCHUNK - 1) / NCHUNK;
    const int e0 = blockIdx.x * per;
    const int e1 = (e0 + per < NE) ? (e0 + per) : NE;
    for (int b = tid; b < NBUK; b += 256)
        lh[b] = bbase[b] + blkcnt[b * NCHUNK + blockIdx.x];
    __syncthreads();
    for (int e = e0 + tid; e < e1; e += 256) {
        int c = col[e], r = row[e];
        int pos = atomicAdd(&lh[c >> 7], 1);
        tmp[pos] = ((unsigned)r << 7) | (unsigned)(c & 127);
    }
}

__global__ __launch_bounds__(256) void k_build(const unsigned* __restrict__ tmp,
                                               const int* __restrict__ bbase,
                                               int* __restrict__ off,
                                               float* __restrict__ dinv,
                                               int* __restrict__ csr_row) {
    __shared__ int cnt[128], s[128], cur[128];
    const int b = blockIdx.x, tid = threadIdx.x;
    const int colBase = b << 7;
    const int nCols = (NN - colBase < 128) ? (NN - colBase) : 128;
    const int seg0 = bbase[b], seg1 = bbase[b + 1];
    if (tid < 128) cnt[tid] = 0;
    __syncthreads();
    for (int i = seg0 + tid; i < seg1; i += 256)
        atomicAdd(&cnt[tmp[i] & 127], 1);
    __syncthreads();
    if (tid < 128) s[tid] = cnt[tid];
    __syncthreads();
    #pragma unroll
    for (int d = 1; d < 128; d <<= 1) {
        int t = (tid < 128 && tid >= d) ? s[tid - d] : 0;
        __syncthreads();
        if (tid < 128) s[tid] += t;
        __syncthreads();
    }
    if (tid < nCols) {
        int exc = seg0 + s[tid] - cnt[tid];
        off[colBase + tid] = exc;
        cur[tid] = exc;
        dinv[colBase + tid] = rsqrtf((float)cnt[tid] + 1.0f);
    }
    if (b == 0 && tid == 0) off[NN] = NE;
    __syncthreads();
    for (int i = seg0 + tid; i < seg1; i += 256) {
        unsigned v = tmp[i];
        int pos = atomicAdd(&cur[v & 127u], 1);
        csr_row[pos] = (int)(v >> 7);
    }
}

// ---------------- fused proj + byp + conv1 GEMM ----------------
// Phase 1: hA_tile = x@projW.T + projb (fp16 out + LDS stash), byp via 5th MFMA n-tile.
// Phase 2 (same block, LDS-resident tile): hB8 = fp8((hA_tile @ convW1.T) * dinv).
__global__ __launch_bounds__(256) void k_gemmPC(const float* __restrict__ X,
                                                const float* __restrict__ W,
                                                const float* __restrict__ bias,
                                                _Float16* __restrict__ Yh,
                                                const float* __restrict__ bypW,
                                                const float* __restrict__ bypb,
                                                float* __restrict__ bypOut,
                                                const float* __restrict__ convW1,
                                                const float* __restrict__ dinv,
                                                unsigned char* __restrict__ Y8,
                                                int n_nodes) {
    constexpr int D = 128, RS = D + 8, KS = D / 32;
    constexpr int RS2 = 72;               // hA tile row stride (halfs)
    __shared__ _Float16 Xh[64 * RS];
    __shared__ _Float16 Wh[64 * RS];
    const int tid = threadIdx.x;
    const int n0 = blockIdx.x * 64;

    for (int i = tid; i < 64 * (D / 8); i += 256) {
        int j = i / (D / 8), d8 = (i % (D / 8)) * 8;
        const float4* wp = (const float4*)&W[j * D + d8];
        float4 w0 = wp[0], w1 = wp[1];
        h8 h = { (_Float16)w0.x, (_Float16)w0.y, (_Float16)w0.z, (_Float16)w0.w,
                 (_Float16)w1.x, (_Float16)w1.y, (_Float16)w1.z, (_Float16)w1.w };
        *(h8*)&Wh[j * RS + d8] = h;
    }
    for (int i = tid; i < 64 * (D / 8); i += 256) {
        int nl = i / (D / 8), d8 = (i % (D / 8)) * 8;
        int n = n0 + nl; if (n >= n_nodes) n = n_nodes - 1;
        const float4* xp = (const float4*)&X[(size_t)n * D + d8];
        float4 x0 = xp[0], x1 = xp[1];
        h8 h = { (_Float16)x0.x, (_Float16)x0.y, (_Float16)x0.z, (_Float16)x0.w,
                 (_Float16)x1.x, (_Float16)x1.y, (_Float16)x1.z, (_Float16)x1.w };
        *(h8*)&Xh[nl * RS + d8] = h;
    }
    __syncthreads();

    const int wid = tid >> 6, lane = tid & 63;
    const int lm = lane & 15, lq = lane >> 4;
    const int mBase = wid * 16;

    h8 bfrag[4][KS];
    #pragma unroll
    for (int t = 0; t < 4; ++t)
        #pragma unroll
        for (int s = 0; s < KS; ++s)
            bfrag[t][s] = *(const h8*)&Wh[(t * 16 + lm) * RS + s * 32 + lq * 8];

    h8 bfragB[KS];
    #pragma unroll
    for (int s = 0; s < KS; ++s) {
        if (lm < 3) {
            const float4* wp = (const float4*)&bypW[lm * D + s * 32 + lq * 8];
            float4 w0 = wp[0], w1 = wp[1];
            bfragB[s] = (h8){ (_Float16)w0.x, (_Float16)w0.y, (_Float16)w0.z, (_Float16)w0.w,
                              (_Float16)w1.x, (_Float16)w1.y, (_Float16)w1.z, (_Float16)w1.w };
        } else {
            bfragB[s] = (h8)(_Float16)0;
        }
    }

    f32x4 acc[5] = {};
    #pragma unroll
    for (int s = 0; s < KS; ++s) {
        h8 a = *(const h8*)&Xh[(mBase + lm) * RS + s * 32 + lq * 8];
        #pragma unroll
        for (int t = 0; t < 4; ++t)
            acc[t] = __builtin_amdgcn_mfma_f32_16x16x32_f16(a, bfrag[t][s], acc[t], 0, 0, 0);
        acc[4] = __builtin_amdgcn_mfma_f32_16x16x32_f16(a, bfragB[s], acc[4], 0, 0, 0);
    }

    float bb[4];
    #pragma unroll
    for (int t = 0; t < 4; ++t) bb[t] = bias[t * 16 + lm];
    float bypbv = (lm < 3) ? bypb[lm] : 0.f;
    const int nodeBase = n0 + mBase + lq * 4;

    __syncthreads();   // all waves done reading Xh/Wh; safe to repurpose

    // epilogue 1: write hA (global fp16 + LDS tile), byp
    #pragma unroll
    for (int r = 0; r < 4; ++r) {
        int node = nodeBase + r;
        int nloc = mBase + lq * 4 + r;
        #pragma unroll
        for (int t = 0; t < 4; ++t) {
            _Float16 hv = (_Float16)(acc[t][r] + bb[t]);
            Xh[nloc * RS2 + t * 16 + lm] = hv;            // stash tile
            if (node < n_nodes)
                Yh[(size_t)node * 64 + t * 16 + lm] = hv;
        }
        if (node < n_nodes && lm < 3)
            bypOut[node * 3 + lm] = acc[4][r] + bypbv;
    }
    // stage convW1 into Wh (fp16, stride RS2)
    for (int i = tid; i < 64 * 8; i += 256) {
        int j = i >> 3, d8 = (i & 7) * 8;
        const float4* wp = (const float4*)&convW1[j * 64 + d8];
        float4 w0 = wp[0], w1 = wp[1];
        h8 h = { (_Float16)w0.x, (_Float16)w0.y, (_Float16)w0.z, (_Float16)w0.w,
                 (_Float16)w1.x, (_Float16)w1.y, (_Float16)w1.z, (_Float16)w1.w };
        *(h8*)&Wh[j * RS2 + d8] = h;
    }
    __syncthreads();

    // phase 2: conv1 MFMA on the LDS-resident hA tile
    h8 cfrag[4][2];
    #pragma unroll
    for (int t = 0; t < 4; ++t)
        #pragma unroll
        for (int s = 0; s < 2; ++s)
            cfrag[t][s] = *(const h8*)&Wh[(t * 16 + lm) * RS2 + s * 32 + lq * 8];

    f32x4 acc2[4] = {};
    #pragma unroll
    for (int s = 0; s < 2; ++s) {
        h8 a = *(const h8*)&Xh[(mBase + lm) * RS2 + s * 32 + lq * 8];
        #pragma unroll
        for (int t = 0; t < 4; ++t)
            acc2[t] = __builtin_amdgcn_mfma_f32_16x16x32_f16(a, cfrag[t][s], acc2[t], 0, 0, 0);
    }
    #pragma unroll
    for (int r = 0; r < 4; ++r) {
        int node = nodeBase + r;
        if (node < n_nodes) {
            float sdv = dinv[node];
            #pragma unroll
            for (int t = 0; t < 4; ++t) {
                float v = acc2[t][r] * sdv;
                int pk = __builtin_amdgcn_cvt_pk_fp8_f32(v, v, 0, false);
                Y8[(size_t)node * 64 + t * 16 + lm] = (unsigned char)(pk & 0xff);
            }
        }
    }
}

// ---------------- conv GEMM (D=64): fp8 e4m3 message output only ----------------
__global__ __launch_bounds__(256) void k_gemmC(const _Float16* __restrict__ Xhg,
                                               const float* __restrict__ W,
                                               const float* __restrict__ dinv,
                                               unsigned char* __restrict__ Y8,
                                               int n_nodes) {
    constexpr int D = 64, RS = D + 8, KS = D / 32;
    __shared__ _Float16 Xh[64 * RS];
    __shared__ _Float16 Wh[64 * RS];
    const int tid = threadIdx.x;
    const int n0 = blockIdx.x * 64;

    for (int i = tid; i < 64 * (D / 8); i += 256) {
        int j = i / (D / 8), d8 = (i % (D / 8)) * 8;
        const float4* wp = (const float4*)&W[j * D + d8];
        float4 w0 = wp[0], w1 = wp[1];
        h8 h = { (_Float16)w0.x, (_Float16)w0.y, (_Float16)w0.z, (_Float16)w0.w,
                 (_Float16)w1.x, (_Float16)w1.y, (_Float16)w1.z, (_Float16)w1.w };
        *(h8*)&Wh[j * RS + d8] = h;
    }
    for (int i = tid; i < 64 * (D / 8); i += 256) {
        int nl = i / (D / 8), d8 = (i % (D / 8)) * 8;
        int n = n0 + nl; if (n >= n_nodes) n = n_nodes - 1;
        *(h8*)&Xh[nl * RS + d8] = *(const h8*)&Xhg[(size_t)n * D + d8];
    }
    __syncthreads();

    const int wid = tid >> 6, lane = tid & 63;
    const int lm = lane & 15, lq = lane >> 4;
    const int mBase = wid * 16;

    h8 bfrag[4][KS];
    #pragma unroll
    for (int t = 0; t < 4; ++t)
        #pragma unroll
        for (int s = 0; s < KS; ++s)
            bfrag[t][s] = *(const h8*)&Wh[(t * 16 + lm) * RS + s * 32 + lq * 8];

    f32x4 acc[4] = {};
    #pragma unroll
    for (int s = 0; s < KS; ++s) {
        h8 a = *(const h8*)&Xh[(mBase + lm) * RS + s * 32 + lq * 8];
        #pragma unroll
        for (int t = 0; t < 4; ++t)
            acc[t] = __builtin_amdgcn_mfma_f32_16x16x32_f16(a, bfrag[t][s], acc[t], 0, 0, 0);
    }

    const int nodeBase = n0 + mBase + lq * 4;
    #pragma unroll
    for (int r = 0; r < 4; ++r) {
        int node = nodeBase + r;
        if (node < n_nodes) {
            float sdv = dinv[node];
            #pragma unroll
            for (int t = 0; t < 4; ++t) {
                float v = acc[t][r] * sdv;
                int pk = __builtin_amdgcn_cvt_pk_fp8_f32(v, v, 0, false);
                Y8[(size_t)node * 64 + t * 16 + lm] = (unsigned char)(pk & 0xff);
            }
        }
    }
}

// ---------------- pull-aggregation: fp8 messages (incl. self), fp32 acc, 8-wide MLP ----------------
template<bool RES, bool HEAD>
__global__ __launch_bounds__(256) void k_gather(const unsigned char* __restrict__ hB8,
                                                const float* __restrict__ dinv,
                                                const int* __restrict__ off,
                                                const int* __restrict__ csr_row,
                                                const float* __restrict__ convb,
                                                const float* __restrict__ bng,
                                                const float* __restrict__ bnb,
                                                _Float16* __restrict__ hA,
                                                const float* __restrict__ byp,
                                                const float* __restrict__ headW,
                                                const float* __restrict__ headb,
                                                float* __restrict__ out) {
    __shared__ float HWs[HEAD ? 204 : 1];
    const int tid = threadIdx.x;
    if constexpr (HEAD) {
        for (int i = tid; i < 204; i += 256)
            HWs[i] = (i < 201) ? headW[i] : headb[i - 201];
        __syncthreads();
    }
    const int wid = tid >> 6, lane = tid & 63;
    const int n = blockIdx.x * 32 + wid * 8 + (lane >> 3);   // grid = NN/32 exactly
    const int oct = lane & 7;
    const int f0 = oct * 8;

    const int e0 = off[n], eEnd = off[n + 1];
    const int deg = eEnd - e0;
    int m = deg;
    #pragma unroll
    for (int mask = 8; mask < 64; mask <<= 1) {
        int o = __shfl_xor(m, mask, 64);
        m = (o > m) ? o : m;
    }

    const uint2* rows8 = (const uint2*)hB8;   // 8 uint2 per node row
    float acc[8] = {0, 0, 0, 0, 0, 0, 0, 0};
    uint2 selfw = rows8[(size_t)n * 8 + oct];
    {
        f32x2 p0 = __builtin_amdgcn_cvt_pk_f32_fp8(selfw.x, false);
        f32x2 p1 = __builtin_amdgcn_cvt_pk_f32_fp8(selfw.x, true);
        f32x2 p2 = __builtin_amdgcn_cvt_pk_f32_fp8(selfw.y, false);
        f32x2 p3 = __builtin_amdgcn_cvt_pk_f32_fp8(selfw.y, true);
        acc[0] += p0.x; acc[1] += p0.y; acc[2] += p1.x; acc[3] += p1.y;
        acc[4] += p2.x; acc[5] += p2.y; acc[6] += p3.x; acc[7] += p3.y;
    }
    for (int it = 0; it < m; it += 8) {
        uint2 w[8];
        #pragma unroll
        for (int q = 0; q < 8; ++q) {
            bool vq = it + q < deg;
            int rq = csr_row[vq ? e0 + it + q : 0];
            w[q] = rows8[(size_t)rq * 8 + oct];
            if (!vq) { w[q].x = 0; w[q].y = 0; }
        }
        #pragma unroll
        for (int q = 0; q < 8; ++q) {
            f32x2 p0 = __builtin_amdgcn_cvt_pk_f32_fp8(w[q].x, false);
            f32x2 p1 = __builtin_amdgcn_cvt_pk_f32_fp8(w[q].x, true);
            f32x2 p2 = __builtin_amdgcn_cvt_pk_f32_fp8(w[q].y, false);
            f32x2 p3 = __builtin_amdgcn_cvt_pk_f32_fp8(w[q].y, true);
            acc[0] += p0.x; acc[1] += p0.y; acc[2] += p1.x; acc[3] += p1.y;
            acc[4] += p2.x; acc[5] += p2.y; acc[6] += p3.x; acc[7] += p3.y;
        }
    }

    const float dv = dinv[n];
    const float bnscale = rsqrtf(1.0f + 1e-5f);
    const float4 cb0 = *(const float4*)&convb[f0], cb1 = *(const float4*)&convb[f0 + 4];
    const float4 g0  = *(const float4*)&bng[f0],  g1  = *(const float4*)&bng[f0 + 4];
    const float4 b0_ = *(const float4*)&bnb[f0],  b1_ = *(const float4*)&bnb[f0 + 4];
    const float cb[8] = { cb0.x, cb0.y, cb0.z, cb0.w, cb1.x, cb1.y, cb1.z, cb1.w };
    const float gg[8] = { g0.x, g0.y, g0.z, g0.w, g1.x, g1.y, g1.z, g1.w };
    const float bb[8] = { b0_.x, b0_.y, b0_.z, b0_.w, b1_.x, b1_.y, b1_.z, b1_.w };
    float v[8];
    #pragma unroll
    for (int j = 0; j < 8; ++j)
        v[j] = fmaxf((acc[j] * dv + cb[j]) * (gg[j] * bnscale) + bb[j], 0.0f);

    if constexpr (!HEAD) {
        size_t o = ((size_t)n << 6) + f0;
        if constexpr (RES) {
            h8 old = *(const h8*)&hA[o];
            #pragma unroll
            for (int j = 0; j < 8; ++j) v[j] += (float)old[j];
        }
        h8 res = { (_Float16)v[0], (_Float16)v[1], (_Float16)v[2], (_Float16)v[3],
                   (_Float16)v[4], (_Float16)v[5], (_Float16)v[6], (_Float16)v[7] };
        *(h8*)&hA[o] = res;
    } else {
        float p[3];
        #pragma unroll
        for (int o = 0; o < 3; ++o) {
            float t = 0.f;
            #pragma unroll
            for (int j = 0; j < 8; ++j) t += v[j] * HWs[o * 67 + f0 + j];
            p[o] = t;
        }
        #pragma unroll
        for (int mask = 1; mask < 8; mask <<= 1) {
            #pragma unroll
            for (int o = 0; o < 3; ++o) p[o] += __shfl_xor(p[o], mask, 64);
        }
        if (oct == 0) {
            float by0 = byp[n * 3], by1 = byp[n * 3 + 1], by2 = byp[n * 3 + 2];
            #pragma unroll
            for (int o = 0; o < 3; ++o)
                p[o] += by0 * HWs[o * 67 + 64] + by1 * HWs[o * 67 + 65] + by2 * HWs[o * 67 + 66]
                      + HWs[201 + o];
            float kappa = fminf(fmaxf(p[0] * 5.0f + 2.5f, 0.2f), 10.0f);
            float tau   = fminf(fmaxf(p[2] + 0.5f, 0.05f), 2.0f);
            out[(size_t)n * 3]     = kappa;
            out[(size_t)n * 3 + 1] = p[1];
            out[(size_t)n * 3 + 2] = tau;
        }
    }
}

extern "C" void kernel_launch(void* const* d_in, const int* in_sizes, int n_in,
                              void* d_out, int out_size, void* d_ws, size_t ws_size,
                              hipStream_t stream) {
    const float* x     = (const float*)d_in[0];
    const int*   ei    = (const int*)d_in[1];
    const int*   row   = ei;
    const int*   col   = ei + NE;
    const float* projW = (const float*)d_in[2];
    const float* projb = (const float*)d_in[3];
    const float* convW[3] = { (const float*)d_in[4], (const float*)d_in[8],  (const float*)d_in[12] };
    const float* convb[3] = { (const float*)d_in[5], (const float*)d_in[9],  (const float*)d_in[13] };
    const float* bng[3]   = { (const float*)d_in[6], (const float*)d_in[10], (const float*)d_in[14] };
    const float* bnb[3]   = { (const float*)d_in[7], (const float*)d_in[11], (const float*)d_in[15] };
    const float* bypW  = (const float*)d_in[16];
    const float* bypb  = (const float*)d_in[17];
    const float* headW = (const float*)d_in[18];
    const float* headb = (const float*)d_in[19];
    float* out = (float*)d_out;

    float*    ws   = (float*)d_ws;
    float*    dinv = ws;                                   // 102400 floats
    _Float16* hAh  = (_Float16*)(ws + 102400);             // NN*64 fp16
    unsigned char* hB8 = (unsigned char*)(hAh + (size_t)NN * 64);  // NN*64 bytes fp8
    float*    byp  = (float*)(hB8 + (size_t)NN * 64);      // NN*3 (+pad 300032)
    int*      off     = (int*)(byp + 300032);              // NN+1 (pad 100096)
    int*      csr_row = off + 100096;                      // NE
    int*      bcnt    = csr_row + NE;                      // NBUK+1 (pad 784)
    int*      blkcnt  = bcnt + 784;                        // NBUK*NCHUNK = 100096
    unsigned* tmp     = (unsigned*)hAh;                    // aliases hAh (consumed before proj)

    // deterministic bucketed CSR build (+dinv +off) — zero global atomics
    k_bucketA<<<NCHUNK, 256, 0, stream>>>(col, blkcnt);
    k_colscan<<<NBUK, 128, 0, stream>>>(blkcnt, bcnt);
    k_bscan<<<1, 1024, 0, stream>>>(bcnt);
    k_bucketB<<<NCHUNK, 256, 0, stream>>>(row, col, bcnt, blkcnt, tmp);
    k_build<<<NBUK, 256, 0, stream>>>(tmp, bcnt, off, dinv, csr_row);

    // fused proj + byp + conv1: hAh, byp, hB8 in one pass
    k_gemmPC<<<(NN + 63) / 64, 256, 0, stream>>>(
        x, projW, projb, hAh, bypW, bypb, byp, convW[0], dinv, hB8, NN);

    for (int l = 0; l < 3; l++) {
        if (l > 0)   // hB8 = fp8((hAh @ convW.T) * dinv)
            k_gemmC<<<(NN + 63) / 64, 256, 0, stream>>>(hAh, convW[l], dinv, hB8, NN);
        if (l < 2)
            k_gather<true, false><<<NN / 32, 256, 0, stream>>>(
                hB8, dinv, off, csr_row, convb[l], bng[l], bnb[l], hAh,
                nullptr, nullptr, nullptr, nullptr);
        else
            k_gather<false, true><<<NN / 32, 256, 0, stream>>>(
                hB8, dinv, off, csr_row, convb[l], bng[l], bnb[l], nullptr,
                byp, headW, headb, out);
    }
}

// Round 21
// 259.577 us; speedup vs baseline: 1.2148x; 1.0006x over previous
//
#include <hip/hip_runtime.h>
#include <hip/hip_fp16.h>

#define NN 100000
#define NE 1200000
#define NBUK ((NN + 127) / 128)   // 782
#define NCHUNK 512                // chunks in bucket passes (2 blocks/CU)

typedef _Float16 h8 __attribute__((ext_vector_type(8)));
typedef float f32x4 __attribute__((ext_vector_type(4)));
typedef float f32x2 __attribute__((ext_vector_type(2)));

// ---------------- deterministic two-phase bucketed CSR build ----------------
__global__ __launch_bounds__(256) void k_bucketA(const int* __restrict__ col,
                                                 int* __restrict__ blkcnt) {
    __shared__ int lh[NBUK];
    const int tid = threadIdx.x;
    const int per = (NE + NCHUNK - 1) / NCHUNK;
    const int e0 = blockIdx.x * per;
    const int e1 = (e0 + per < NE) ? (e0 + per) : NE;
    for (int i = tid; i < NBUK; i += 256) lh[i] = 0;
    __syncthreads();
    for (int e = e0 + tid; e < e1; e += 256)
        atomicAdd(&lh[col[e] >> 7], 1);
    __syncthreads();
    for (int b = tid; b < NBUK; b += 256)
        blkcnt[b * NCHUNK + blockIdx.x] = lh[b];
}

__global__ __launch_bounds__(512) void k_colscan(int* __restrict__ blkcnt, int* __restrict__ bcnt) {
    __shared__ int s[NCHUNK];
    const int b = blockIdx.x, tid = threadIdx.x;
    int v = blkcnt[b * NCHUNK + tid];
    s[tid] = v;
    __syncthreads();
    #pragma unroll
    for (int d = 1; d < NCHUNK; d <<= 1) {
        int t = (tid >= d) ? s[tid - d] : 0;
        __syncthreads();
        s[tid] += t;
        __syncthreads();
    }
    blkcnt[b * NCHUNK + tid] = s[tid] - v;   // exclusive prefix within bucket
    if (tid == NCHUNK - 1) bcnt[b] = s[NCHUNK - 1];
}

__global__ __launch_bounds__(1024) void k_bscan(int* __restrict__ bcnt) {
    __shared__ int s[1024];
    int tid = threadIdx.x;
    int v = (tid < NBUK) ? bcnt[tid] : 0;
    s[tid] = v;
    __syncthreads();
    #pragma unroll
    for (int d = 1; d < 1024; d <<= 1) {
        int t = (tid >= d) ? s[tid - d] : 0;
        __syncthreads();
        s[tid] += t;
        __syncthreads();
    }
    if (tid < NBUK) bcnt[tid] = s[tid] - v;
    if (tid == 0) bcnt[NBUK] = NE;
}

__global__ __launch_bounds__(256) void k_bucketB(const int* __restrict__ row,
                                                 const int* __restrict__ col,
                                                 const int* __restrict__ bbase,
                                                 const int* __restrict__ blkcnt,
                                                 unsigned* __restrict__ tmp) {
    __shared__ int lh[NBUK];
    const int tid = threadIdx.x;
    const int per = (NE + NCHUNK - 1) / NCHUNK;
    const int e0 = blockIdx.x * per;
    const int e1 = (e0 + per < NE) ? (e0 + per) : NE;
    for (int b = tid; b < NBUK; b += 256)
        lh[b] = bbase[b] + blkcnt[b * NCHUNK + blockIdx.x];
    __syncthreads();
    for (int e = e0 + tid; e < e1; e += 256) {
        int c = col[e], r = row[e];
        int pos = atomicAdd(&lh[c >> 7], 1);
        tmp[pos] = ((unsigned)r << 7) | (unsigned)(c & 127);
    }
}

__global__ __launch_bounds__(256) void k_build(const unsigned* __restrict__ tmp,
                                               const int* __restrict__ bbase,
                                               int* __restrict__ off,
                                               float* __restrict__ dinv,
                                               int* __restrict__ csr_row) {
    __shared__ int cnt[128], s[128], cur[128];
    const int b = blockIdx.x, tid = threadIdx.x;
    const int colBase = b << 7;
    const int nCols = (NN - colBase < 128) ? (NN - colBase) : 128;
    const int seg0 = bbase[b], seg1 = bbase[b + 1];
    if (tid < 128) cnt[tid] = 0;
    __syncthreads();
    for (int i = seg0 + tid; i < seg1; i += 256)
        atomicAdd(&cnt[tmp[i] & 127], 1);
    __syncthreads();
    if (tid < 128) s[tid] = cnt[tid];
    __syncthreads();
    #pragma unroll
    for (int d = 1; d < 128; d <<= 1) {
        int t = (tid < 128 && tid >= d) ? s[tid - d] : 0;
        __syncthreads();
        if (tid < 128) s[tid] += t;
        __syncthreads();
    }
    if (tid < nCols) {
        int exc = seg0 + s[tid] - cnt[tid];
        off[colBase + tid] = exc;
        cur[tid] = exc;
        dinv[colBase + tid] = rsqrtf((float)cnt[tid] + 1.0f);
    }
    if (b == 0 && tid == 0) off[NN] = NE;
    __syncthreads();
    for (int i = seg0 + tid; i < seg1; i += 256) {
        unsigned v = tmp[i];
        int pos = atomicAdd(&cur[v & 127u], 1);
        csr_row[pos] = (int)(v >> 7);
    }
}

// ---------------- fused proj + byp + conv1 GEMM ----------------
__global__ __launch_bounds__(256) void k_gemmPC(const float* __restrict__ X,
                                                const float* __restrict__ W,
                                                const float* __restrict__ bias,
                                                _Float16* __restrict__ Yh,
                                                const float* __restrict__ bypW,
                                                const float* __restrict__ bypb,
                                                float* __restrict__ bypOut,
                                                const float* __restrict__ convW1,
                                                const float* __restrict__ dinv,
                                                unsigned char* __restrict__ Y8,
                                                int n_nodes) {
    constexpr int D = 128, RS = D + 8, KS = D / 32;
    constexpr int RS2 = 72;               // hA tile row stride (halfs)
    __shared__ _Float16 Xh[64 * RS];
    __shared__ _Float16 Wh[64 * RS];
    const int tid = threadIdx.x;
    const int n0 = blockIdx.x * 64;

    for (int i = tid; i < 64 * (D / 8); i += 256) {
        int j = i / (D / 8), d8 = (i % (D / 8)) * 8;
        const float4* wp = (const float4*)&W[j * D + d8];
        float4 w0 = wp[0], w1 = wp[1];
        h8 h = { (_Float16)w0.x, (_Float16)w0.y, (_Float16)w0.z, (_Float16)w0.w,
                 (_Float16)w1.x, (_Float16)w1.y, (_Float16)w1.z, (_Float16)w1.w };
        *(h8*)&Wh[j * RS + d8] = h;
    }
    for (int i = tid; i < 64 * (D / 8); i += 256) {
        int nl = i / (D / 8), d8 = (i % (D / 8)) * 8;
        int n = n0 + nl; if (n >= n_nodes) n = n_nodes - 1;
        const float4* xp = (const float4*)&X[(size_t)n * D + d8];
        float4 x0 = xp[0], x1 = xp[1];
        h8 h = { (_Float16)x0.x, (_Float16)x0.y, (_Float16)x0.z, (_Float16)x0.w,
                 (_Float16)x1.x, (_Float16)x1.y, (_Float16)x1.z, (_Float16)x1.w };
        *(h8*)&Xh[nl * RS + d8] = h;
    }
    __syncthreads();

    const int wid = tid >> 6, lane = tid & 63;
    const int lm = lane & 15, lq = lane >> 4;
    const int mBase = wid * 16;

    h8 bfrag[4][KS];
    #pragma unroll
    for (int t = 0; t < 4; ++t)
        #pragma unroll
        for (int s = 0; s < KS; ++s)
            bfrag[t][s] = *(const h8*)&Wh[(t * 16 + lm) * RS + s * 32 + lq * 8];

    h8 bfragB[KS];
    #pragma unroll
    for (int s = 0; s < KS; ++s) {
        if (lm < 3) {
            const float4* wp = (const float4*)&bypW[lm * D + s * 32 + lq * 8];
            float4 w0 = wp[0], w1 = wp[1];
            bfragB[s] = (h8){ (_Float16)w0.x, (_Float16)w0.y, (_Float16)w0.z, (_Float16)w0.w,
                              (_Float16)w1.x, (_Float16)w1.y, (_Float16)w1.z, (_Float16)w1.w };
        } else {
            bfragB[s] = (h8)(_Float16)0;
        }
    }

    f32x4 acc[5] = {};
    #pragma unroll
    for (int s = 0; s < KS; ++s) {
        h8 a = *(const h8*)&Xh[(mBase + lm) * RS + s * 32 + lq * 8];
        #pragma unroll
        for (int t = 0; t < 4; ++t)
            acc[t] = __builtin_amdgcn_mfma_f32_16x16x32_f16(a, bfrag[t][s], acc[t], 0, 0, 0);
        acc[4] = __builtin_amdgcn_mfma_f32_16x16x32_f16(a, bfragB[s], acc[4], 0, 0, 0);
    }

    float bb[4];
    #pragma unroll
    for (int t = 0; t < 4; ++t) bb[t] = bias[t * 16 + lm];
    float bypbv = (lm < 3) ? bypb[lm] : 0.f;
    const int nodeBase = n0 + mBase + lq * 4;

    __syncthreads();   // all waves done reading Xh/Wh; safe to repurpose

    #pragma unroll
    for (int r = 0; r < 4; ++r) {
        int node = nodeBase + r;
        int nloc = mBase + lq * 4 + r;
        #pragma unroll
        for (int t = 0; t < 4; ++t) {
            _Float16 hv = (_Float16)(acc[t][r] + bb[t]);
            Xh[nloc * RS2 + t * 16 + lm] = hv;            // stash tile
            if (node < n_nodes)
                Yh[(size_t)node * 64 + t * 16 + lm] = hv;
        }
        if (node < n_nodes && lm < 3)
            bypOut[node * 3 + lm] = acc[4][r] + bypbv;
    }
    for (int i = tid; i < 64 * 8; i += 256) {
        int j = i >> 3, d8 = (i & 7) * 8;
        const float4* wp = (const float4*)&convW1[j * 64 + d8];
        float4 w0 = wp[0], w1 = wp[1];
        h8 h = { (_Float16)w0.x, (_Float16)w0.y, (_Float16)w0.z, (_Float16)w0.w,
                 (_Float16)w1.x, (_Float16)w1.y, (_Float16)w1.z, (_Float16)w1.w };
        *(h8*)&Wh[j * RS2 + d8] = h;
    }
    __syncthreads();

    h8 cfrag[4][2];
    #pragma unroll
    for (int t = 0; t < 4; ++t)
        #pragma unroll
        for (int s = 0; s < 2; ++s)
            cfrag[t][s] = *(const h8*)&Wh[(t * 16 + lm) * RS2 + s * 32 + lq * 8];

    f32x4 acc2[4] = {};
    #pragma unroll
    for (int s = 0; s < 2; ++s) {
        h8 a = *(const h8*)&Xh[(mBase + lm) * RS2 + s * 32 + lq * 8];
        #pragma unroll
        for (int t = 0; t < 4; ++t)
            acc2[t] = __builtin_amdgcn_mfma_f32_16x16x32_f16(a, cfrag[t][s], acc2[t], 0, 0, 0);
    }
    #pragma unroll
    for (int r = 0; r < 4; ++r) {
        int node = nodeBase + r;
        if (node < n_nodes) {
            float sdv = dinv[node];
            #pragma unroll
            for (int t = 0; t < 4; ++t) {
                float v = acc2[t][r] * sdv;
                int pk = __builtin_amdgcn_cvt_pk_fp8_f32(v, v, 0, false);
                Y8[(size_t)node * 64 + t * 16 + lm] = (unsigned char)(pk & 0xff);
            }
        }
    }
}

// ---------------- conv GEMM (D=64): fp8 e4m3 message output only ----------------
__global__ __launch_bounds__(256) void k_gemmC(const _Float16* __restrict__ Xhg,
                                               const float* __restrict__ W,
                                               const float* __restrict__ dinv,
                                               unsigned char* __restrict__ Y8,
                                               int n_nodes) {
    constexpr int D = 64, RS = D + 8, KS = D / 32;
    __shared__ _Float16 Xh[64 * RS];
    __shared__ _Float16 Wh[64 * RS];
    const int tid = threadIdx.x;
    const int n0 = blockIdx.x * 64;

    for (int i = tid; i < 64 * (D / 8); i += 256) {
        int j = i / (D / 8), d8 = (i % (D / 8)) * 8;
        const float4* wp = (const float4*)&W[j * D + d8];
        float4 w0 = wp[0], w1 = wp[1];
        h8 h = { (_Float16)w0.x, (_Float16)w0.y, (_Float16)w0.z, (_Float16)w0.w,
                 (_Float16)w1.x, (_Float16)w1.y, (_Float16)w1.z, (_Float16)w1.w };
        *(h8*)&Wh[j * RS + d8] = h;
    }
    for (int i = tid; i < 64 * (D / 8); i += 256) {
        int nl = i / (D / 8), d8 = (i % (D / 8)) * 8;
        int n = n0 + nl; if (n >= n_nodes) n = n_nodes - 1;
        *(h8*)&Xh[nl * RS + d8] = *(const h8*)&Xhg[(size_t)n * D + d8];
    }
    __syncthreads();

    const int wid = tid >> 6, lane = tid & 63;
    const int lm = lane & 15, lq = lane >> 4;
    const int mBase = wid * 16;

    h8 bfrag[4][KS];
    #pragma unroll
    for (int t = 0; t < 4; ++t)
        #pragma unroll
        for (int s = 0; s < KS; ++s)
            bfrag[t][s] = *(const h8*)&Wh[(t * 16 + lm) * RS + s * 32 + lq * 8];

    f32x4 acc[4] = {};
    #pragma unroll
    for (int s = 0; s < KS; ++s) {
        h8 a = *(const h8*)&Xh[(mBase + lm) * RS + s * 32 + lq * 8];
        #pragma unroll
        for (int t = 0; t < 4; ++t)
            acc[t] = __builtin_amdgcn_mfma_f32_16x16x32_f16(a, bfrag[t][s], acc[t], 0, 0, 0);
    }

    const int nodeBase = n0 + mBase + lq * 4;
    #pragma unroll
    for (int r = 0; r < 4; ++r) {
        int node = nodeBase + r;
        if (node < n_nodes) {
            float sdv = dinv[node];
            #pragma unroll
            for (int t = 0; t < 4; ++t) {
                float v = acc[t][r] * sdv;
                int pk = __builtin_amdgcn_cvt_pk_fp8_f32(v, v, 0, false);
                Y8[(size_t)node * 64 + t * 16 + lm] = (unsigned char)(pk & 0xff);
            }
        }
    }
}

// ---------------- pull-aggregation: fp8 messages (incl. self), fp32 acc, 8-wide MLP ----------------
template<bool RES, bool HEAD>
__global__ __launch_bounds__(256) void k_gather(const unsigned char* __restrict__ hB8,
                                                const float* __restrict__ dinv,
                                                const int* __restrict__ off,
                                                const int* __restrict__ csr_row,
                                                const float* __restrict__ convb,
                                                const float* __restrict__ bng,
                                                const float* __restrict__ bnb,
                                                _Float16* __restrict__ hA,
                                                const float* __restrict__ byp,
                                                const float* __restrict__ headW,
                                                const float* __restrict__ headb,
                                                float* __restrict__ out) {
    __shared__ float HWs[HEAD ? 204 : 1];
    const int tid = threadIdx.x;
    if constexpr (HEAD) {
        for (int i = tid; i < 204; i += 256)
            HWs[i] = (i < 201) ? headW[i] : headb[i - 201];
        __syncthreads();
    }
    const int wid = tid >> 6, lane = tid & 63;
    const int n = blockIdx.x * 32 + wid * 8 + (lane >> 3);   // grid = NN/32 exactly
    const int oct = lane & 7;
    const int f0 = oct * 8;

    const int e0 = off[n], eEnd = off[n + 1];
    const int deg = eEnd - e0;
    int m = deg;
    #pragma unroll
    for (int mask = 8; mask < 64; mask <<= 1) {
        int o = __shfl_xor(m, mask, 64);
        m = (o > m) ? o : m;
    }

    const uint2* rows8 = (const uint2*)hB8;   // 8 uint2 per node row
    float acc[8] = {0, 0, 0, 0, 0, 0, 0, 0};
    uint2 selfw = rows8[(size_t)n * 8 + oct];
    {
        f32x2 p0 = __builtin_amdgcn_cvt_pk_f32_fp8(selfw.x, false);
        f32x2 p1 = __builtin_amdgcn_cvt_pk_f32_fp8(selfw.x, true);
        f32x2 p2 = __builtin_amdgcn_cvt_pk_f32_fp8(selfw.y, false);
        f32x2 p3 = __builtin_amdgcn_cvt_pk_f32_fp8(selfw.y, true);
        acc[0] += p0.x; acc[1] += p0.y; acc[2] += p1.x; acc[3] += p1.y;
        acc[4] += p2.x; acc[5] += p2.y; acc[6] += p3.x; acc[7] += p3.y;
    }
    for (int it = 0; it < m; it += 8) {
        uint2 w[8];
        #pragma unroll
        for (int q = 0; q < 8; ++q) {
            bool vq = it + q < deg;
            int rq = csr_row[vq ? e0 + it + q : 0];
            w[q] = rows8[(size_t)rq * 8 + oct];
            if (!vq) { w[q].x = 0; w[q].y = 0; }
        }
        #pragma unroll
        for (int q = 0; q < 8; ++q) {
            f32x2 p0 = __builtin_amdgcn_cvt_pk_f32_fp8(w[q].x, false);
            f32x2 p1 = __builtin_amdgcn_cvt_pk_f32_fp8(w[q].x, true);
            f32x2 p2 = __builtin_amdgcn_cvt_pk_f32_fp8(w[q].y, false);
            f32x2 p3 = __builtin_amdgcn_cvt_pk_f32_fp8(w[q].y, true);
            acc[0] += p0.x; acc[1] += p0.y; acc[2] += p1.x; acc[3] += p1.y;
            acc[4] += p2.x; acc[5] += p2.y; acc[6] += p3.x; acc[7] += p3.y;
        }
    }

    const float dv = dinv[n];
    const float bnscale = rsqrtf(1.0f + 1e-5f);
    const float4 cb0 = *(const float4*)&convb[f0], cb1 = *(const float4*)&convb[f0 + 4];
    const float4 g0  = *(const float4*)&bng[f0],  g1  = *(const float4*)&bng[f0 + 4];
    const float4 b0_ = *(const float4*)&bnb[f0],  b1_ = *(const float4*)&bnb[f0 + 4];
    const float cb[8] = { cb0.x, cb0.y, cb0.z, cb0.w, cb1.x, cb1.y, cb1.z, cb1.w };
    const float gg[8] = { g0.x, g0.y, g0.z, g0.w, g1.x, g1.y, g1.z, g1.w };
    const float bb[8] = { b0_.x, b0_.y, b0_.z, b0_.w, b1_.x, b1_.y, b1_.z, b1_.w };
    float v[8];
    #pragma unroll
    for (int j = 0; j < 8; ++j)
        v[j] = fmaxf((acc[j] * dv + cb[j]) * (gg[j] * bnscale) + bb[j], 0.0f);

    if constexpr (!HEAD) {
        size_t o = ((size_t)n << 6) + f0;
        if constexpr (RES) {
            h8 old = *(const h8*)&hA[o];
            #pragma unroll
            for (int j = 0; j < 8; ++j) v[j] += (float)old[j];
        }
        h8 res = { (_Float16)v[0], (_Float16)v[1], (_Float16)v[2], (_Float16)v[3],
                   (_Float16)v[4], (_Float16)v[5], (_Float16)v[6], (_Float16)v[7] };
        *(h8*)&hA[o] = res;
    } else {
        float p[3];
        #pragma unroll
        for (int o = 0; o < 3; ++o) {
            float t = 0.f;
            #pragma unroll
            for (int j = 0; j < 8; ++j) t += v[j] * HWs[o * 67 + f0 + j];
            p[o] = t;
        }
        #pragma unroll
        for (int mask = 1; mask < 8; mask <<= 1) {
            #pragma unroll
            for (int o = 0; o < 3; ++o) p[o] += __shfl_xor(p[o], mask, 64);
        }
        if (oct == 0) {
            float by0 = byp[n * 3], by1 = byp[n * 3 + 1], by2 = byp[n * 3 + 2];
            #pragma unroll
            for (int o = 0; o < 3; ++o)
                p[o] += by0 * HWs[o * 67 + 64] + by1 * HWs[o * 67 + 65] + by2 * HWs[o * 67 + 66]
                      + HWs[201 + o];
            float kappa = fminf(fmaxf(p[0] * 5.0f + 2.5f, 0.2f), 10.0f);
            float tau   = fminf(fmaxf(p[2] + 0.5f, 0.05f), 2.0f);
            out[(size_t)n * 3]     = kappa;
            out[(size_t)n * 3 + 1] = p[1];
            out[(size_t)n * 3 + 2] = tau;
        }
    }
}

extern "C" void kernel_launch(void* const* d_in, const int* in_sizes, int n_in,
                              void* d_out, int out_size, void* d_ws, size_t ws_size,
                              hipStream_t stream) {
    const float* x     = (const float*)d_in[0];
    const int*   ei    = (const int*)d_in[1];
    const int*   row   = ei;
    const int*   col   = ei + NE;
    const float* projW = (const float*)d_in[2];
    const float* projb = (const float*)d_in[3];
    const float* convW[3] = { (const float*)d_in[4], (const float*)d_in[8],  (const float*)d_in[12] };
    const float* convb[3] = { (const float*)d_in[5], (const float*)d_in[9],  (const float*)d_in[13] };
    const float* bng[3]   = { (const float*)d_in[6], (const float*)d_in[10], (const float*)d_in[14] };
    const float* bnb[3]   = { (const float*)d_in[7], (const float*)d_in[11], (const float*)d_in[15] };
    const float* bypW  = (const float*)d_in[16];
    const float* bypb  = (const float*)d_in[17];
    const float* headW = (const float*)d_in[18];
    const float* headb = (const float*)d_in[19];
    float* out = (float*)d_out;

    float*    ws   = (float*)d_ws;
    float*    dinv = ws;                                   // 102400 floats
    _Float16* hAh  = (_Float16*)(ws + 102400);             // NN*64 fp16
    unsigned char* hB8 = (unsigned char*)(hAh + (size_t)NN * 64);  // NN*64 bytes fp8
    float*    byp  = (float*)(hB8 + (size_t)NN * 64);      // NN*3 (+pad 300032)
    int*      off     = (int*)(byp + 300032);              // NN+1 (pad 100096)
    int*      csr_row = off + 100096;                      // NE
    int*      bcnt    = csr_row + NE;                      // NBUK+1 (pad 784)
    int*      blkcnt  = bcnt + 784;                        // NBUK*NCHUNK = 400384
    unsigned* tmp     = (unsigned*)hAh;                    // aliases hAh (consumed before proj)

    // deterministic bucketed CSR build (+dinv +off) — zero global atomics
    k_bucketA<<<NCHUNK, 256, 0, stream>>>(col, blkcnt);
    k_colscan<<<NBUK, NCHUNK, 0, stream>>>(blkcnt, bcnt);
    k_bscan<<<1, 1024, 0, stream>>>(bcnt);
    k_bucketB<<<NCHUNK, 256, 0, stream>>>(row, col, bcnt, blkcnt, tmp);
    k_build<<<NBUK, 256, 0, stream>>>(tmp, bcnt, off, dinv, csr_row);

    // fused proj + byp + conv1: hAh, byp, hB8 in one pass
    k_gemmPC<<<(NN + 63) / 64, 256, 0, stream>>>(
        x, projW, projb, hAh, bypW, bypb, byp, convW[0], dinv, hB8, NN);

    for (int l = 0; l < 3; l++) {
        if (l > 0)   // hB8 = fp8((hAh @ convW.T) * dinv)
            k_gemmC<<<(NN + 63) / 64, 256, 0, stream>>>(hAh, convW[l], dinv, hB8, NN);
        if (l < 2)
            k_gather<true, false><<<NN / 32, 256, 0, stream>>>(
                hB8, dinv, off, csr_row, convb[l], bng[l], bnb[l], hAh,
                nullptr, nullptr, nullptr, nullptr);
        else
            k_gather<false, true><<<NN / 32, 256, 0, stream>>>(
                hB8, dinv, off, csr_row, convb[l], bng[l], bnb[l], nullptr,
                byp, headW, headb, out);
    }
}